// Round 7
// baseline (390.976 us; speedup 1.0000x reference)
//
#include <hip/hip_runtime.h>

// ---------------------------------------------------------------------------
// Types / helpers
// ---------------------------------------------------------------------------
typedef __bf16 bf16x8 __attribute__((ext_vector_type(8)));
typedef float  f32x4  __attribute__((ext_vector_type(4)));

union U8 { bf16x8 v; __bf16 e[8]; unsigned short u[8]; };

__device__ __forceinline__ unsigned short f2bf(float f) {
  unsigned int u = __float_as_uint(f);
  unsigned int r = (u + 0x7FFFu + ((u >> 16) & 1u)) >> 16;  // RNE
  return (unsigned short)r;
}

__device__ __forceinline__ void async16(const void* g, void* l) {
  __builtin_amdgcn_global_load_lds(
      (__attribute__((address_space(1))) void*)(g),
      (__attribute__((address_space(3))) void*)(l), 16, 0, 0);
}

__device__ __forceinline__ void block_barrier() {
  asm volatile("" ::: "memory");
  __builtin_amdgcn_sched_barrier(0);
  __builtin_amdgcn_s_barrier();
  __builtin_amdgcn_sched_barrier(0);
  asm volatile("" ::: "memory");
}

// ---------------------------------------------------------------------------
// Batched transpose: in fp32 [batch][R][Cc] -> out bf16 [batch*Cc + c][R]
// ---------------------------------------------------------------------------
__global__ __launch_bounds__(256) void transpose_w(
    const float* __restrict__ in, unsigned short* __restrict__ out,
    int R, int Cc) {
  __shared__ float tile[32][33];
  const int batch = blockIdx.z;
  const float* ip = in + (size_t)batch * R * Cc;
  unsigned short* op = out + (size_t)batch * R * Cc;
  const int c0 = blockIdx.x * 32, r0 = blockIdx.y * 32;
  const int tx = threadIdx.x, ty = threadIdx.y;  // 32 x 8
#pragma unroll
  for (int i = 0; i < 32; i += 8)
    tile[ty + i][tx] = ip[(size_t)(r0 + ty + i) * Cc + c0 + tx];
  __syncthreads();
#pragma unroll
  for (int i = 0; i < 32; i += 8)
    op[(size_t)(c0 + ty + i) * R + r0 + tx] = f2bf(tile[tx][ty + i]);
}

// ---------------------------------------------------------------------------
// LayerNorm over rows of 1024, fp32 in -> bf16 out.
// ---------------------------------------------------------------------------
__global__ __launch_bounds__(256) void ln_kernel(
    const float* __restrict__ x, const float* __restrict__ g,
    const float* __restrict__ bta, unsigned short* __restrict__ out) {
  const int C = 1024;
  const int row = blockIdx.x, tid = threadIdx.x;
  const float4 v = ((const float4*)(x + (size_t)row * C))[tid];
  float s  = v.x + v.y + v.z + v.w;
  float ss = v.x * v.x + v.y * v.y + v.z * v.z + v.w * v.w;
#pragma unroll
  for (int off = 32; off > 0; off >>= 1) {
    s  += __shfl_down(s, off);
    ss += __shfl_down(ss, off);
  }
  __shared__ float r0[4], r1[4];
  const int wave = tid >> 6, lane = tid & 63;
  if (lane == 0) { r0[wave] = s; r1[wave] = ss; }
  __syncthreads();
  s  = r0[0] + r0[1] + r0[2] + r0[3];
  ss = r1[0] + r1[1] + r1[2] + r1[3];
  const float mu   = s * (1.0f / C);
  const float var  = ss * (1.0f / C) - mu * mu;
  const float rstd = rsqrtf(var + 1e-5f);
  const float4 gv = ((const float4*)g)[tid];
  const float4 bv = ((const float4*)bta)[tid];
  ushort4 o;
  o.x = f2bf((v.x - mu) * rstd * gv.x + bv.x);
  o.y = f2bf((v.y - mu) * rstd * gv.y + bv.y);
  o.z = f2bf((v.z - mu) * rstd * gv.z + bv.z);
  o.w = f2bf((v.w - mu) * rstd * gv.w + bv.w);
  ((ushort4*)(out + (size_t)row * C))[tid] = o;
}

// ---------------------------------------------------------------------------
// Register-pipelined LDS-FREE GEMM for the latency-bound N=1024 shapes.
// C[M][N] = A[M][K]*BT[N][K]^T + bias + resid -> fp32.
// 128x64 tile, 4 waves (2m x 2n), per-wave 64x32 out (acc[4][2]).
// MFMA fragments are loaded DIRECTLY from global per lane
// (global_load_dwordx4, perfectly coalesced) -- no LDS, no barriers, no
// convoy. 2 K-tile (BK=64) frag sets double-buffered in a hand-unrolled
// x2 loop; loads for tiles t+2/t+3 issue between MFMA blocks; compiler
// emits per-use counted vmcnt. Cross-wave operand duplication (2x) is
// served by L1/L2 (16KB slices). 512 blocks = 2/CU; waves stall
// independently (no block-wide barrier).
// ---------------------------------------------------------------------------
__global__ __launch_bounds__(256, 2) void gemm_reg(
    const unsigned short* __restrict__ A, const unsigned short* __restrict__ BT,
    float* __restrict__ Cout, const float* __restrict__ bias,
    const float* __restrict__ resid, int M, int N, int K) {
  const int tid = threadIdx.x;
  const int lane = tid & 63, wave = tid >> 6;
  const int wm = wave >> 1, wn = wave & 1;
  const int lr = lane & 15, lg = lane >> 4;

  // XCD-bijective swizzle + GROUP_M=4 supertiling (nwg % 8 == 0)
  const int nwg = gridDim.x;
  const int cpx = nwg >> 3;
  const int swz = ((int)blockIdx.x & 7) * cpx + ((int)blockIdx.x >> 3);
  const int Nt = N >> 6;
  const int g4 = swz / (4 * Nt);
  const int rem = swz - g4 * 4 * Nt;
  const int m0 = (g4 * 4 + (rem & 3)) << 7;
  const int n0 = (rem >> 2) << 6;

  // per-lane fragment row pointers (include lane k-offset lg*8)
  const unsigned short* pa0 = A + (size_t)(m0 + wm * 64 +  0 + lr) * K + lg * 8;
  const unsigned short* pa1 = A + (size_t)(m0 + wm * 64 + 16 + lr) * K + lg * 8;
  const unsigned short* pa2 = A + (size_t)(m0 + wm * 64 + 32 + lr) * K + lg * 8;
  const unsigned short* pa3 = A + (size_t)(m0 + wm * 64 + 48 + lr) * K + lg * 8;
  const unsigned short* pb0 = BT + (size_t)(n0 + wn * 32 +  0 + lr) * K + lg * 8;
  const unsigned short* pb1 = BT + (size_t)(n0 + wn * 32 + 16 + lr) * K + lg * 8;

  bf16x8 a0[2][4], b0[2][2], a1[2][4], b1[2][2];
  f32x4 acc[4][2] = {};

  // load tile-pair frag sets: T0 at ptr+{0,32}, T1 at ptr+{64,96} (elements)
#define LD_T0                                                     \
  {                                                               \
    _Pragma("unroll")                                             \
    for (int kh = 0; kh < 2; kh++) {                              \
      a0[kh][0] = *(const bf16x8*)(pa0 + kh * 32);                \
      a0[kh][1] = *(const bf16x8*)(pa1 + kh * 32);                \
      a0[kh][2] = *(const bf16x8*)(pa2 + kh * 32);                \
      a0[kh][3] = *(const bf16x8*)(pa3 + kh * 32);                \
      b0[kh][0] = *(const bf16x8*)(pb0 + kh * 32);                \
      b0[kh][1] = *(const bf16x8*)(pb1 + kh * 32);                \
    }                                                             \
  }
#define LD_T1                                                     \
  {                                                               \
    _Pragma("unroll")                                             \
    for (int kh = 0; kh < 2; kh++) {                              \
      a1[kh][0] = *(const bf16x8*)(pa0 + 64 + kh * 32);           \
      a1[kh][1] = *(const bf16x8*)(pa1 + 64 + kh * 32);           \
      a1[kh][2] = *(const bf16x8*)(pa2 + 64 + kh * 32);           \
      a1[kh][3] = *(const bf16x8*)(pa3 + 64 + kh * 32);           \
      b1[kh][0] = *(const bf16x8*)(pb0 + 64 + kh * 32);           \
      b1[kh][1] = *(const bf16x8*)(pb1 + 64 + kh * 32);           \
    }                                                             \
  }
#define ADV { pa0 += 128; pa1 += 128; pa2 += 128; pa3 += 128; pb0 += 128; pb1 += 128; }
#define FMAS(aa, bb)                                                        \
  {                                                                         \
    _Pragma("unroll")                                                       \
    for (int kh = 0; kh < 2; kh++)                                          \
      _Pragma("unroll")                                                     \
      for (int fm = 0; fm < 4; fm++)                                        \
        _Pragma("unroll")                                                   \
        for (int fn = 0; fn < 2; fn++)                                      \
          acc[fm][fn] = __builtin_amdgcn_mfma_f32_16x16x32_bf16(            \
              aa[kh][fm], bb[kh][fn], acc[fm][fn], 0, 0, 0);                \
  }

  const int niter = K >> 7;  // two BK=64 tiles per iteration (K % 128 == 0)
  LD_T0;
  LD_T1;
  ADV;
#pragma unroll 1
  for (int i = 0; i < niter - 1; ++i) {
    FMAS(a0, b0);
    LD_T0;              // tiles 2i+2
    FMAS(a1, b1);
    LD_T1;              // tiles 2i+3
    ADV;
  }
  FMAS(a0, b0);
  FMAS(a1, b1);

#undef LD_T0
#undef LD_T1
#undef ADV
#undef FMAS

#pragma unroll
  for (int fn = 0; fn < 2; fn++) {
    const int col = n0 + wn * 32 + fn * 16 + lr;
    const float bv = bias[col];
#pragma unroll
    for (int fm = 0; fm < 4; fm++) {
      const int row0 = m0 + wm * 64 + fm * 16 + lg * 4;
#pragma unroll
      for (int r = 0; r < 4; r++) {
        const size_t idx = (size_t)(row0 + r) * N + col;
        Cout[idx] = acc[fm][fn][r] + bv + resid[idx];
      }
    }
  }
}

// ---------------------------------------------------------------------------
// 256x256 8-phase deep-pipelined GEMM (unchanged).
// EPI: 2 = relu(+bias) -> bf16 ; 4 = QKV split
// ---------------------------------------------------------------------------
template <int EPI>
__global__ __launch_bounds__(512, 2) void gemm8p(
    const unsigned short* __restrict__ A, const unsigned short* __restrict__ BT,
    void* __restrict__ Cout, void* __restrict__ Cout2,
    const float* __restrict__ bias, int M, int N, int K) {
  __shared__ __align__(16) unsigned short As[2][2][8192];
  __shared__ __align__(16) unsigned short Bs[2][2][8192];
  const int tid = threadIdx.x;
  const int lane = tid & 63;
  const int wave = tid >> 6;
  const int wm = wave >> 2, wn = wave & 3;  // 2 x 4 wave grid
  const int lr = lane & 15, lg = lane >> 4;

  const int nwg = gridDim.x;
  const int cpx = nwg >> 3;
  const int swz = ((int)blockIdx.x & 7) * cpx + ((int)blockIdx.x >> 3);
  const int Nt = N >> 8;
  const int g4 = swz / (4 * Nt);
  const int rem = swz - g4 * 4 * Nt;
  const int m0 = (g4 * 4 + (rem & 3)) << 8;
  const int n0 = (rem >> 2) << 8;

  const int srow = tid >> 2;
  const int scg = ((tid & 3) ^ ((srow >> 1) & 3)) << 3;
  const unsigned short* Ag = A + (size_t)(m0 + srow) * K + scg;
  const unsigned short* Bg = BT + (size_t)(n0 + srow) * K + scg;
  const size_t rskip = (size_t)128 * K;
  const int l8 = tid * 8;

  const int kch = (lg ^ ((lr >> 1) & 3)) << 3;

  f32x4 acc[8][4] = {};
  bf16x8 afr[4], bfr[4];
  const int nkt = K >> 6;

  async16(Ag, &As[0][0][l8]);            async16(Ag + rskip, &As[0][0][l8 + 4096]);
  async16(Bg, &Bs[0][0][l8]);            async16(Bg + rskip, &Bs[0][0][l8 + 4096]);
  async16(Ag + 32, &As[0][1][l8]);       async16(Ag + 32 + rskip, &As[0][1][l8 + 4096]);
  async16(Bg + 32, &Bs[0][1][l8]);       async16(Bg + 32 + rskip, &Bs[0][1][l8 + 4096]);
  async16(Ag + 64, &As[1][0][l8]);       async16(Ag + 64 + rskip, &As[1][0][l8 + 4096]);
  async16(Bg + 64, &Bs[1][0][l8]);       async16(Bg + 64 + rskip, &Bs[1][0][l8 + 4096]);
  asm volatile("s_waitcnt vmcnt(4)" ::: "memory");
  block_barrier();

  for (int t = 0; t < nkt; ++t) {
    const int buf = t & 1, nbuf = buf ^ 1;
    const int kt1 = (t + 1) << 6, kt2 = (t + 2) << 6;
    const bool s1 = (t + 1 < nkt), s2 = (t + 2 < nkt);

    // ---- phase 1: ks=0, mh=0 ----
#pragma unroll
    for (int fm = 0; fm < 4; fm++)
      afr[fm] = *(const bf16x8*)&As[buf][0][(wm * 128 + fm * 16 + lr) * 32 + kch];
#pragma unroll
    for (int fn = 0; fn < 4; fn++)
      bfr[fn] = *(const bf16x8*)&Bs[buf][0][(wn * 64 + fn * 16 + lr) * 32 + kch];
    if (s1) {
      async16(Ag + kt1 + 32, &As[nbuf][1][l8]);
      async16(Ag + kt1 + 32 + rskip, &As[nbuf][1][l8 + 4096]);
    }
    block_barrier();
    __builtin_amdgcn_s_setprio(1);
#pragma unroll
    for (int fm = 0; fm < 4; fm++)
#pragma unroll
      for (int fn = 0; fn < 4; fn++)
        acc[fm][fn] = __builtin_amdgcn_mfma_f32_16x16x32_bf16(afr[fm], bfr[fn], acc[fm][fn], 0, 0, 0);
    __builtin_amdgcn_s_setprio(0);
    block_barrier();

    // ---- phase 2: ks=0, mh=1 ----
#pragma unroll
    for (int fm = 0; fm < 4; fm++)
      afr[fm] = *(const bf16x8*)&As[buf][0][(wm * 128 + 64 + fm * 16 + lr) * 32 + kch];
    if (s1) {
      async16(Bg + kt1 + 32, &Bs[nbuf][1][l8]);
      async16(Bg + kt1 + 32 + rskip, &Bs[nbuf][1][l8 + 4096]);
    }
    block_barrier();
    __builtin_amdgcn_s_setprio(1);
#pragma unroll
    for (int fm = 0; fm < 4; fm++)
#pragma unroll
      for (int fn = 0; fn < 4; fn++)
        acc[4 + fm][fn] = __builtin_amdgcn_mfma_f32_16x16x32_bf16(afr[fm], bfr[fn], acc[4 + fm][fn], 0, 0, 0);
    __builtin_amdgcn_s_setprio(0);
    block_barrier();

    // ---- phase 3: ks=1, mh=0 ----
#pragma unroll
    for (int fm = 0; fm < 4; fm++)
      afr[fm] = *(const bf16x8*)&As[buf][1][(wm * 128 + fm * 16 + lr) * 32 + kch];
#pragma unroll
    for (int fn = 0; fn < 4; fn++)
      bfr[fn] = *(const bf16x8*)&Bs[buf][1][(wn * 64 + fn * 16 + lr) * 32 + kch];
    if (s2) {
      async16(Ag + kt2, &As[buf][0][l8]);
      async16(Ag + kt2 + rskip, &As[buf][0][l8 + 4096]);
    }
    block_barrier();
    __builtin_amdgcn_s_setprio(1);
#pragma unroll
    for (int fm = 0; fm < 4; fm++)
#pragma unroll
      for (int fn = 0; fn < 4; fn++)
        acc[fm][fn] = __builtin_amdgcn_mfma_f32_16x16x32_bf16(afr[fm], bfr[fn], acc[fm][fn], 0, 0, 0);
    __builtin_amdgcn_s_setprio(0);
    block_barrier();

    // ---- phase 4: ks=1, mh=1 ----
#pragma unroll
    for (int fm = 0; fm < 4; fm++)
      afr[fm] = *(const bf16x8*)&As[buf][1][(wm * 128 + 64 + fm * 16 + lr) * 32 + kch];
    if (s2) {
      async16(Bg + kt2, &Bs[buf][0][l8]);
      async16(Bg + kt2 + rskip, &Bs[buf][0][l8 + 4096]);
    }
    block_barrier();
    __builtin_amdgcn_s_setprio(1);
#pragma unroll
    for (int fm = 0; fm < 4; fm++)
#pragma unroll
      for (int fn = 0; fn < 4; fn++)
        acc[4 + fm][fn] = __builtin_amdgcn_mfma_f32_16x16x32_bf16(afr[fm], bfr[fn], acc[4 + fm][fn], 0, 0, 0);
    __builtin_amdgcn_s_setprio(0);
    if (s2) asm volatile("s_waitcnt vmcnt(4)" ::: "memory");
    else    asm volatile("s_waitcnt vmcnt(0)" ::: "memory");
    block_barrier();
  }

#pragma unroll
  for (int fn = 0; fn < 4; fn++) {
    const int col = n0 + wn * 64 + fn * 16 + lr;
    float bv = 0.0f;
    if (EPI == 2) bv = bias[col];
#pragma unroll
    for (int fm = 0; fm < 8; fm++) {
      const int row0 = m0 + wm * 128 + fm * 16 + lg * 4;
      if (EPI == 2) {
#pragma unroll
        for (int r = 0; r < 4; r++)
          ((unsigned short*)Cout)[(size_t)(row0 + r) * N + col] =
              f2bf(fmaxf(acc[fm][fn][r] + bv, 0.0f));
      } else {  // EPI 4: QKV split
        if (col < 2048) {
#pragma unroll
          for (int r = 0; r < 4; r++)
            ((unsigned short*)Cout)[(size_t)(row0 + r) * 2048 + col] =
                f2bf(acc[fm][fn][r]);
        } else {
          ushort4 ov;
          ov.x = f2bf(acc[fm][fn][0]);
          ov.y = f2bf(acc[fm][fn][1]);
          ov.z = f2bf(acc[fm][fn][2]);
          ov.w = f2bf(acc[fm][fn][3]);
          *(ushort4*)((unsigned short*)Cout2 + (size_t)(col - 2048) * 4096 + row0) = ov;
        }
      }
    }
  }
}

// ---------------------------------------------------------------------------
// Flash attention (causal), swapped-operand, LDS-staged K/V, double-buffered.
// (unchanged)
// ---------------------------------------------------------------------------
__global__ __launch_bounds__(256) void attn_kernel(
    const unsigned short* __restrict__ qk, const unsigned short* __restrict__ vT,
    unsigned short* __restrict__ o) {
  const int T = 2048, C = 1024, QKS = 2048;
  const int tid = threadIdx.x;
  const int wave = tid >> 6, lane = tid & 63;
  const int lr = lane & 15, lg = lane >> 4;
  const int b = blockIdx.y >> 4, hh = blockIdx.y & 15;
  const size_t rowb = (size_t)b * T * QKS;
  const int qcol = hh * 64;
  const int kcol = 1024 + hh * 64;
  const int vrow0 = hh * 64;
  const size_t bT = (size_t)b * T;
  const int swe = (lr & 7) << 3;

  __shared__ __align__(16) unsigned short Ks[2][64 * 64];
  __shared__ __align__(16) unsigned short Vs[2][64 * 64];
  __shared__ __align__(16) unsigned short Ps[4][16][72];

  const int rw = tid >> 3;
  const int c8 = ((tid & 7) ^ (rw & 7)) << 3;

#pragma unroll 1
  for (int pass = 0; pass < 2; ++pass) {
    const int qt = (pass == 0) ? (int)blockIdx.x : (31 - (int)blockIdx.x);
    const int qbase = qt * 64 + wave * 16;
    const int trow = qbase + lr;

    U8 qf[2];
#pragma unroll
    for (int j = 0; j < 2; j++)
      qf[j].v = *(const bf16x8*)(qk + rowb + (size_t)trow * QKS + qcol + j * 32 + lg * 8);
    asm volatile("s_waitcnt vmcnt(0)" ::: "memory");

    async16(qk + rowb + (size_t)rw * QKS + kcol + c8, Ks[0] + tid * 8);
    async16(qk + rowb + (size_t)(32 + rw) * QKS + kcol + c8, Ks[0] + 2048 + tid * 8);
    async16(vT + (size_t)(vrow0 + rw) * 4096 + bT + c8, Vs[0] + tid * 8);
    async16(vT + (size_t)(vrow0 + 32 + rw) * 4096 + bT + c8, Vs[0] + 2048 + tid * 8);

    f32x4 oa[4] = {};
    float mrun = -1e30f, lsum = 0.0f;
    int cur = 0;

    for (int sb = 0; sb <= qt; ++sb) {
      if (sb < qt) {
        const int s1 = (sb + 1) * 64;
        const int nb = cur ^ 1;
        async16(qk + rowb + (size_t)(s1 + rw) * QKS + kcol + c8, Ks[nb] + tid * 8);
        async16(qk + rowb + (size_t)(s1 + 32 + rw) * QKS + kcol + c8, Ks[nb] + 2048 + tid * 8);
        async16(vT + (size_t)(vrow0 + rw) * 4096 + bT + s1 + c8, Vs[nb] + tid * 8);
        async16(vT + (size_t)(vrow0 + 32 + rw) * 4096 + bT + s1 + c8, Vs[nb] + 2048 + tid * 8);
        asm volatile("s_waitcnt vmcnt(4)" ::: "memory");
      } else {
        asm volatile("s_waitcnt vmcnt(0)" ::: "memory");
      }
      block_barrier();

      const unsigned short* Kc = Ks[cur];
      const unsigned short* Vc = Vs[cur];
      const int s0 = sb * 64;

      f32x4 sa[4] = {};
#pragma unroll
      for (int j = 0; j < 2; j++) {
#pragma unroll
        for (int mf = 0; mf < 4; mf++) {
          U8 kf;
          kf.v = *(const bf16x8*)(Kc + (mf * 16 + lr) * 64 + ((j * 32 + lg * 8) ^ swe));
          sa[mf] = __builtin_amdgcn_mfma_f32_16x16x32_bf16(kf.v, qf[j].v, sa[mf], 0, 0, 0);
        }
      }
      float sv[16];
#pragma unroll
      for (int mf = 0; mf < 4; mf++)
#pragma unroll
        for (int r = 0; r < 4; r++) sv[mf * 4 + r] = sa[mf][r] * 0.125f;

      if (sb == qt) {
#pragma unroll
        for (int mf = 0; mf < 4; mf++)
#pragma unroll
          for (int r = 0; r < 4; r++)
            if (s0 + mf * 16 + lg * 4 + r > trow) sv[mf * 4 + r] = -1e30f;
      }

      float tm = sv[0];
#pragma unroll
      for (int i = 1; i < 16; i++) tm = fmaxf(tm, sv[i]);
      tm = fmaxf(tm, __shfl_xor(tm, 16));
      tm = fmaxf(tm, __shfl_xor(tm, 32));

      if (!__all(tm <= mrun + 8.0f)) {
        const float mn = fmaxf(mrun, tm);
        const float corr = __expf(mrun - mn);
        lsum *= corr;
#pragma unroll
        for (int c = 0; c < 4; c++)
#pragma unroll
          for (int r = 0; r < 4; r++) oa[c][r] *= corr;
        mrun = mn;
      }

      float rs = 0.0f;
#pragma unroll
      for (int i = 0; i < 16; i++) {
        sv[i] = __expf(sv[i] - mrun);
        rs += sv[i];
      }
      rs += __shfl_xor(rs, 16);
      rs += __shfl_xor(rs, 32);
      lsum += rs;

#pragma unroll
      for (int mf = 0; mf < 4; mf++) {
        ushort4 w;
        w.x = f2bf(sv[mf * 4 + 0]);
        w.y = f2bf(sv[mf * 4 + 1]);
        w.z = f2bf(sv[mf * 4 + 2]);
        w.w = f2bf(sv[mf * 4 + 3]);
        *(ushort4*)&Ps[wave][lr][mf * 16 + lg * 4] = w;
      }
      asm volatile("" ::: "memory");
      U8 pb[2];
      pb[0].v = *(const bf16x8*)&Ps[wave][lr][lg * 8];
      pb[1].v = *(const bf16x8*)&Ps[wave][lr][32 + lg * 8];
      asm volatile("" ::: "memory");

#pragma unroll
      for (int c = 0; c < 4; c++) {
#pragma unroll
        for (int ks = 0; ks < 2; ks++) {
          U8 vf;
          vf.v = *(const bf16x8*)(Vc + (c * 16 + lr) * 64 + ((ks * 32 + lg * 8) ^ swe));
          oa[c] = __builtin_amdgcn_mfma_f32_16x16x32_bf16(vf.v, pb[ks].v, oa[c], 0, 0, 0);
        }
      }

      block_barrier();
      cur ^= 1;
    }

    const float inv = 1.0f / lsum;
#pragma unroll
    for (int c = 0; c < 4; c++) {
      ushort4 ov;
      ov.x = f2bf(oa[c][0] * inv);
      ov.y = f2bf(oa[c][1] * inv);
      ov.z = f2bf(oa[c][2] * inv);
      ov.w = f2bf(oa[c][3] * inv);
      *(ushort4*)(o + (size_t)(bT + trow) * C + hh * 64 + c * 16 + lg * 4) = ov;
    }
  }
}

// ---------------------------------------------------------------------------
// Orchestration
// ---------------------------------------------------------------------------
extern "C" void kernel_launch(void* const* d_in, const int* in_sizes, int n_in,
                              void* d_out, int out_size, void* d_ws, size_t ws_size,
                              hipStream_t stream) {
  (void)in_sizes; (void)n_in; (void)out_size; (void)ws_size;
  const int T = 2048, C = 1024, M = 2 * T, C4 = 4 * C;

  const float* x     = (const float*)d_in[0];
  const float* Wq    = (const float*)d_in[1];
  const float* Wk    = (const float*)d_in[2];
  const float* Wv    = (const float*)d_in[3];
  const float* Wproj = (const float*)d_in[4];
  const float* bproj = (const float*)d_in[5];
  const float* W1    = (const float*)d_in[6];
  const float* b1    = (const float*)d_in[7];
  const float* W2    = (const float*)d_in[8];
  const float* b2    = (const float*)d_in[9];
  const float* ln1g  = (const float*)d_in[10];
  const float* ln1b  = (const float*)d_in[11];
  const float* ln2g  = (const float*)d_in[12];
  const float* ln2b  = (const float*)d_in[13];
  float* out = (float*)d_out;

  char* ws = (char*)d_ws;
  const size_t MBy = (size_t)1 << 20;
  unsigned short* WqkvT = (unsigned short*)(ws + 0 * MBy);  // 6 MB [3072][1024]
  unsigned short* WqT = WqkvT;
  unsigned short* WkT = WqkvT + 1024 * 1024;
  unsigned short* WvT = WqkvT + 2048 * 1024;
  unsigned short* WpT = (unsigned short*)(ws + 6 * MBy);    // 2 MB
  unsigned short* W1T = (unsigned short*)(ws + 8 * MBy);    // 8 MB
  unsigned short* W2T = (unsigned short*)(ws + 16 * MBy);   // 8 MB
  unsigned short* h   = (unsigned short*)(ws + 24 * MBy);   // 8 MB  [4096][1024]
  unsigned short* qkb = (unsigned short*)(ws + 32 * MBy);   // 16 MB [4096][2048]
  unsigned short* vTb = (unsigned short*)(ws + 48 * MBy);   // 8 MB  [1024][4096]
  unsigned short* att = (unsigned short*)(ws + 56 * MBy);   // 8 MB
  float*          x1  = (float*)(ws + 64 * MBy);            // 16 MB
  unsigned short* h2  = att;                                // reuse
  unsigned short* ff1 = h;                                  // reuse h/qkb/vTb

  const dim3 tb(32, 8);
  transpose_w<<<dim3(2, 32, 16), tb, 0, stream>>>(Wq, WqT, 1024, 64);
  transpose_w<<<dim3(2, 32, 16), tb, 0, stream>>>(Wk, WkT, 1024, 64);
  transpose_w<<<dim3(2, 32, 16), tb, 0, stream>>>(Wv, WvT, 1024, 64);
  transpose_w<<<dim3(32, 32, 1), tb, 0, stream>>>(Wproj, WpT, 1024, 1024);
  transpose_w<<<dim3(128, 32, 1), tb, 0, stream>>>(W1, W1T, 1024, 4096);
  transpose_w<<<dim3(32, 128, 1), tb, 0, stream>>>(W2, W2T, 4096, 1024);

  ln_kernel<<<M, 256, 0, stream>>>(x, ln1g, ln1b, h);

  // Fused QKV (8-phase 256^2): N=3072; cols<2048 -> qkb, cols>=2048 -> vTb^T
  gemm8p<4><<<192, 512, 0, stream>>>(h, WqkvT, qkb, vTb, nullptr, M, 3072, C);

  attn_kernel<<<dim3(16, 32), 256, 0, stream>>>(qkb, vTb, att);

  // proj (+bias+resid) -> fp32, LDS-free register-pipelined GEMM
  gemm_reg<<<512, 256, 0, stream>>>(att, WpT, x1, bproj, x, M, C, C);

  ln_kernel<<<M, 256, 0, stream>>>(x1, ln2g, ln2b, h2);

  // FFN1 (8-phase 256^2): relu(h2 @ W1 + b1) -> bf16
  gemm8p<2><<<256, 512, 0, stream>>>(h2, W1T, ff1, nullptr, b1, M, C4, C);

  // FFN2 (+bias+resid) -> fp32, LDS-free register-pipelined GEMM
  gemm_reg<<<512, 256, 0, stream>>>(ff1, W2T, out, b2, x1, M, C, C4);
}

// Round 8
// 272.664 us; speedup vs baseline: 1.4339x; 1.4339x over previous
//
#include <hip/hip_runtime.h>

// ---------------------------------------------------------------------------
// Types / helpers
// ---------------------------------------------------------------------------
typedef __bf16 bf16x8 __attribute__((ext_vector_type(8)));
typedef float  f32x4  __attribute__((ext_vector_type(4)));

union U8 { bf16x8 v; __bf16 e[8]; unsigned short u[8]; };

__device__ __forceinline__ unsigned short f2bf(float f) {
  unsigned int u = __float_as_uint(f);
  unsigned int r = (u + 0x7FFFu + ((u >> 16) & 1u)) >> 16;  // RNE
  return (unsigned short)r;
}

__device__ __forceinline__ void async16(const void* g, void* l) {
  __builtin_amdgcn_global_load_lds(
      (__attribute__((address_space(1))) void*)(g),
      (__attribute__((address_space(3))) void*)(l), 16, 0, 0);
}

__device__ __forceinline__ void block_barrier() {
  asm volatile("" ::: "memory");
  __builtin_amdgcn_sched_barrier(0);
  __builtin_amdgcn_s_barrier();
  __builtin_amdgcn_sched_barrier(0);
  asm volatile("" ::: "memory");
}

// ---------------------------------------------------------------------------
// Batched transpose: in fp32 [batch][R][Cc] -> out bf16 [batch*Cc + c][R]
// ---------------------------------------------------------------------------
__global__ __launch_bounds__(256) void transpose_w(
    const float* __restrict__ in, unsigned short* __restrict__ out,
    int R, int Cc) {
  __shared__ float tile[32][33];
  const int batch = blockIdx.z;
  const float* ip = in + (size_t)batch * R * Cc;
  unsigned short* op = out + (size_t)batch * R * Cc;
  const int c0 = blockIdx.x * 32, r0 = blockIdx.y * 32;
  const int tx = threadIdx.x, ty = threadIdx.y;  // 32 x 8
#pragma unroll
  for (int i = 0; i < 32; i += 8)
    tile[ty + i][tx] = ip[(size_t)(r0 + ty + i) * Cc + c0 + tx];
  __syncthreads();
#pragma unroll
  for (int i = 0; i < 32; i += 8)
    op[(size_t)(c0 + ty + i) * R + r0 + tx] = f2bf(tile[tx][ty + i]);
}

// ---------------------------------------------------------------------------
// LayerNorm over rows of 1024, fp32 in -> bf16 out.
// ---------------------------------------------------------------------------
__global__ __launch_bounds__(256) void ln_kernel(
    const float* __restrict__ x, const float* __restrict__ g,
    const float* __restrict__ bta, unsigned short* __restrict__ out) {
  const int C = 1024;
  const int row = blockIdx.x, tid = threadIdx.x;
  const float4 v = ((const float4*)(x + (size_t)row * C))[tid];
  float s  = v.x + v.y + v.z + v.w;
  float ss = v.x * v.x + v.y * v.y + v.z * v.z + v.w * v.w;
#pragma unroll
  for (int off = 32; off > 0; off >>= 1) {
    s  += __shfl_down(s, off);
    ss += __shfl_down(ss, off);
  }
  __shared__ float r0[4], r1[4];
  const int wave = tid >> 6, lane = tid & 63;
  if (lane == 0) { r0[wave] = s; r1[wave] = ss; }
  __syncthreads();
  s  = r0[0] + r0[1] + r0[2] + r0[3];
  ss = r1[0] + r1[1] + r1[2] + r1[3];
  const float mu   = s * (1.0f / C);
  const float var  = ss * (1.0f / C) - mu * mu;
  const float rstd = rsqrtf(var + 1e-5f);
  const float4 gv = ((const float4*)g)[tid];
  const float4 bv = ((const float4*)bta)[tid];
  ushort4 o;
  o.x = f2bf((v.x - mu) * rstd * gv.x + bv.x);
  o.y = f2bf((v.y - mu) * rstd * gv.y + bv.y);
  o.z = f2bf((v.z - mu) * rstd * gv.z + bv.z);
  o.w = f2bf((v.w - mu) * rstd * gv.w + bv.w);
  ((ushort4*)(out + (size_t)row * C))[tid] = o;
}

// ---------------------------------------------------------------------------
// Split-K GEMM for the latency-bound N=1024 shapes.
// Partial[ks][M][N] (fp32, NO bias/resid) = A[M][K-slice] * BT[N][K-slice]^T.
// 128x64 tile, 4 waves (2m x 2n), BK=64, DOUBLE-buffered 48 KB LDS ->
// 3 blocks/CU (launch_bounds(256,3)); split-K=2 doubles the grid to 1024
// blocks so 3/CU residency is actually used. 2-phase schedule: STG(t+1)
// after prev end-barrier (race-free), counted vmcnt(6), compute, barrier.
// Chunk-XOR swizzle via pre-swizzled global source (verified 0 conflicts).
// ---------------------------------------------------------------------------
__global__ __launch_bounds__(256, 3) void gemm_sk(
    const unsigned short* __restrict__ A, const unsigned short* __restrict__ BT,
    float* __restrict__ P0, float* __restrict__ P1,
    int M, int N, int K) {
  __shared__ __align__(16) unsigned short As[2][8192];  // [128 rows][64 k]
  __shared__ __align__(16) unsigned short Bs[2][4096];  // [64 rows][64 k]
  const int tid = threadIdx.x;
  const int lane = tid & 63, wave = tid >> 6;
  const int wm = wave >> 1, wn = wave & 1;
  const int lr = lane & 15, lg = lane >> 4;

  // XCD-bijective swizzle; adjacent swz pairs = same tile, 2 k-slices
  const int nwg = gridDim.x;                 // = 2 * (M/128)*(N/64)
  const int cpx = nwg >> 3;
  const int swz = ((int)blockIdx.x & 7) * cpx + ((int)blockIdx.x >> 3);
  const int tile = swz >> 1, ks = swz & 1;
  const int Nt = N >> 6;
  const int g4 = tile / (4 * Nt);
  const int rem = tile - g4 * 4 * Nt;
  const int m0 = (g4 * 4 + (rem & 3)) << 7;
  const int n0 = (rem >> 2) << 6;
  const int K2 = K >> 1;
  const int k0 = ks * K2;

  const int srow = tid >> 3;
  const int sc = ((tid & 7) ^ (srow & 7)) << 3;
  const unsigned short* Ag = A + (size_t)(m0 + srow) * K + k0 + sc;
  const unsigned short* Bg = BT + (size_t)(n0 + srow) * K + k0 + sc;
  const size_t rskip = (size_t)32 * K;

  f32x4 acc[4][2] = {};
  const int nkt = K2 >> 6;

#define STG(T, B)                                                          \
  {                                                                        \
    const int kt_ = (T) << 6;                                              \
    _Pragma("unroll")                                                      \
    for (int j = 0; j < 4; ++j)                                            \
      async16(Ag + kt_ + (size_t)j * rskip, &As[B][j * 2048 + tid * 8]);   \
    async16(Bg + kt_, &Bs[B][tid * 8]);                                    \
    async16(Bg + kt_ + rskip, &Bs[B][2048 + tid * 8]);                     \
  }

  STG(0, 0);

  for (int t = 0; t < nkt; ++t) {
    const int buf = t & 1;
    if (t + 1 < nkt) {
      STG(t + 1, buf ^ 1);                                   // loads in flight
      asm volatile("s_waitcnt vmcnt(6)" ::: "memory");       // tile t ready
    } else {
      asm volatile("s_waitcnt vmcnt(0)" ::: "memory");
    }
    block_barrier();  // all waves' tile-t loads landed
#pragma unroll
    for (int kh = 0; kh < 2; ++kh) {
      const int kc = ((kh * 4 + lg) ^ (lr & 7)) << 3;
      bf16x8 afr[4], bfr[2];
#pragma unroll
      for (int fm = 0; fm < 4; fm++)
        afr[fm] = *(const bf16x8*)&As[buf][(wm * 64 + fm * 16 + lr) * 64 + kc];
#pragma unroll
      for (int fn = 0; fn < 2; fn++)
        bfr[fn] = *(const bf16x8*)&Bs[buf][(wn * 32 + fn * 16 + lr) * 64 + kc];
#pragma unroll
      for (int fm = 0; fm < 4; fm++)
#pragma unroll
        for (int fn = 0; fn < 2; fn++)
          acc[fm][fn] = __builtin_amdgcn_mfma_f32_16x16x32_bf16(
              afr[fm], bfr[fn], acc[fm][fn], 0, 0, 0);
    }
    block_barrier();  // all waves done reading buf -> next STG may overwrite
  }
#undef STG

  float* P = ks ? P1 : P0;
#pragma unroll
  for (int fn = 0; fn < 2; fn++) {
    const int col = n0 + wn * 32 + fn * 16 + lr;
#pragma unroll
    for (int fm = 0; fm < 4; fm++) {
      const int row0 = m0 + wm * 64 + fm * 16 + lg * 4;
#pragma unroll
      for (int r = 0; r < 4; r++)
        P[(size_t)(row0 + r) * N + col] = acc[fm][fn][r];
    }
  }
}

// ---------------------------------------------------------------------------
// Streaming split-K reduce: out[i] = p0[i] + p1[i] + bias[col] + resid[i].
// resid may alias out (elementwise read-then-write). float4, grid-stride.
// ---------------------------------------------------------------------------
__global__ __launch_bounds__(256) void reduce_add(
    const float* __restrict__ p0, const float* __restrict__ p1,
    const float* __restrict__ bias, const float* __restrict__ resid,
    float* __restrict__ out, int n4) {
  const int stride = gridDim.x * 256;
  for (int i = blockIdx.x * 256 + threadIdx.x; i < n4; i += stride) {
    const float4 a = ((const float4*)p0)[i];
    const float4 b = ((const float4*)p1)[i];
    const float4 c = ((const float4*)resid)[i];
    const float4 bv = ((const float4*)bias)[i & 255];  // N=1024 -> 256 float4
    float4 o;
    o.x = a.x + b.x + c.x + bv.x;
    o.y = a.y + b.y + c.y + bv.y;
    o.z = a.z + b.z + c.z + bv.z;
    o.w = a.w + b.w + c.w + bv.w;
    ((float4*)out)[i] = o;
  }
}

// ---------------------------------------------------------------------------
// 256x256 8-phase deep-pipelined GEMM (unchanged).
// EPI: 2 = relu(+bias) -> bf16 ; 4 = QKV split
// ---------------------------------------------------------------------------
template <int EPI>
__global__ __launch_bounds__(512, 2) void gemm8p(
    const unsigned short* __restrict__ A, const unsigned short* __restrict__ BT,
    void* __restrict__ Cout, void* __restrict__ Cout2,
    const float* __restrict__ bias, int M, int N, int K) {
  __shared__ __align__(16) unsigned short As[2][2][8192];
  __shared__ __align__(16) unsigned short Bs[2][2][8192];
  const int tid = threadIdx.x;
  const int lane = tid & 63;
  const int wave = tid >> 6;
  const int wm = wave >> 2, wn = wave & 3;  // 2 x 4 wave grid
  const int lr = lane & 15, lg = lane >> 4;

  const int nwg = gridDim.x;
  const int cpx = nwg >> 3;
  const int swz = ((int)blockIdx.x & 7) * cpx + ((int)blockIdx.x >> 3);
  const int Nt = N >> 8;
  const int g4 = swz / (4 * Nt);
  const int rem = swz - g4 * 4 * Nt;
  const int m0 = (g4 * 4 + (rem & 3)) << 8;
  const int n0 = (rem >> 2) << 8;

  const int srow = tid >> 2;
  const int scg = ((tid & 3) ^ ((srow >> 1) & 3)) << 3;
  const unsigned short* Ag = A + (size_t)(m0 + srow) * K + scg;
  const unsigned short* Bg = BT + (size_t)(n0 + srow) * K + scg;
  const size_t rskip = (size_t)128 * K;
  const int l8 = tid * 8;

  const int kch = (lg ^ ((lr >> 1) & 3)) << 3;

  f32x4 acc[8][4] = {};
  bf16x8 afr[4], bfr[4];
  const int nkt = K >> 6;

  async16(Ag, &As[0][0][l8]);            async16(Ag + rskip, &As[0][0][l8 + 4096]);
  async16(Bg, &Bs[0][0][l8]);            async16(Bg + rskip, &Bs[0][0][l8 + 4096]);
  async16(Ag + 32, &As[0][1][l8]);       async16(Ag + 32 + rskip, &As[0][1][l8 + 4096]);
  async16(Bg + 32, &Bs[0][1][l8]);       async16(Bg + 32 + rskip, &Bs[0][1][l8 + 4096]);
  async16(Ag + 64, &As[1][0][l8]);       async16(Ag + 64 + rskip, &As[1][0][l8 + 4096]);
  async16(Bg + 64, &Bs[1][0][l8]);       async16(Bg + 64 + rskip, &Bs[1][0][l8 + 4096]);
  asm volatile("s_waitcnt vmcnt(4)" ::: "memory");
  block_barrier();

  for (int t = 0; t < nkt; ++t) {
    const int buf = t & 1, nbuf = buf ^ 1;
    const int kt1 = (t + 1) << 6, kt2 = (t + 2) << 6;
    const bool s1 = (t + 1 < nkt), s2 = (t + 2 < nkt);

    // ---- phase 1: ks=0, mh=0 ----
#pragma unroll
    for (int fm = 0; fm < 4; fm++)
      afr[fm] = *(const bf16x8*)&As[buf][0][(wm * 128 + fm * 16 + lr) * 32 + kch];
#pragma unroll
    for (int fn = 0; fn < 4; fn++)
      bfr[fn] = *(const bf16x8*)&Bs[buf][0][(wn * 64 + fn * 16 + lr) * 32 + kch];
    if (s1) {
      async16(Ag + kt1 + 32, &As[nbuf][1][l8]);
      async16(Ag + kt1 + 32 + rskip, &As[nbuf][1][l8 + 4096]);
    }
    block_barrier();
    __builtin_amdgcn_s_setprio(1);
#pragma unroll
    for (int fm = 0; fm < 4; fm++)
#pragma unroll
      for (int fn = 0; fn < 4; fn++)
        acc[fm][fn] = __builtin_amdgcn_mfma_f32_16x16x32_bf16(afr[fm], bfr[fn], acc[fm][fn], 0, 0, 0);
    __builtin_amdgcn_s_setprio(0);
    block_barrier();

    // ---- phase 2: ks=0, mh=1 ----
#pragma unroll
    for (int fm = 0; fm < 4; fm++)
      afr[fm] = *(const bf16x8*)&As[buf][0][(wm * 128 + 64 + fm * 16 + lr) * 32 + kch];
    if (s1) {
      async16(Bg + kt1 + 32, &Bs[nbuf][1][l8]);
      async16(Bg + kt1 + 32 + rskip, &Bs[nbuf][1][l8 + 4096]);
    }
    block_barrier();
    __builtin_amdgcn_s_setprio(1);
#pragma unroll
    for (int fm = 0; fm < 4; fm++)
#pragma unroll
      for (int fn = 0; fn < 4; fn++)
        acc[4 + fm][fn] = __builtin_amdgcn_mfma_f32_16x16x32_bf16(afr[fm], bfr[fn], acc[4 + fm][fn], 0, 0, 0);
    __builtin_amdgcn_s_setprio(0);
    block_barrier();

    // ---- phase 3: ks=1, mh=0 ----
#pragma unroll
    for (int fm = 0; fm < 4; fm++)
      afr[fm] = *(const bf16x8*)&As[buf][1][(wm * 128 + fm * 16 + lr) * 32 + kch];
#pragma unroll
    for (int fn = 0; fn < 4; fn++)
      bfr[fn] = *(const bf16x8*)&Bs[buf][1][(wn * 64 + fn * 16 + lr) * 32 + kch];
    if (s2) {
      async16(Ag + kt2, &As[buf][0][l8]);
      async16(Ag + kt2 + rskip, &As[buf][0][l8 + 4096]);
    }
    block_barrier();
    __builtin_amdgcn_s_setprio(1);
#pragma unroll
    for (int fm = 0; fm < 4; fm++)
#pragma unroll
      for (int fn = 0; fn < 4; fn++)
        acc[fm][fn] = __builtin_amdgcn_mfma_f32_16x16x32_bf16(afr[fm], bfr[fn], acc[fm][fn], 0, 0, 0);
    __builtin_amdgcn_s_setprio(0);
    block_barrier();

    // ---- phase 4: ks=1, mh=1 ----
#pragma unroll
    for (int fm = 0; fm < 4; fm++)
      afr[fm] = *(const bf16x8*)&As[buf][1][(wm * 128 + 64 + fm * 16 + lr) * 32 + kch];
    if (s2) {
      async16(Bg + kt2, &Bs[buf][0][l8]);
      async16(Bg + kt2 + rskip, &Bs[buf][0][l8 + 4096]);
    }
    block_barrier();
    __builtin_amdgcn_s_setprio(1);
#pragma unroll
    for (int fm = 0; fm < 4; fm++)
#pragma unroll
      for (int fn = 0; fn < 4; fn++)
        acc[4 + fm][fn] = __builtin_amdgcn_mfma_f32_16x16x32_bf16(afr[fm], bfr[fn], acc[4 + fm][fn], 0, 0, 0);
    __builtin_amdgcn_s_setprio(0);
    if (s2) asm volatile("s_waitcnt vmcnt(4)" ::: "memory");
    else    asm volatile("s_waitcnt vmcnt(0)" ::: "memory");
    block_barrier();
  }

#pragma unroll
  for (int fn = 0; fn < 4; fn++) {
    const int col = n0 + wn * 64 + fn * 16 + lr;
    float bv = 0.0f;
    if (EPI == 2) bv = bias[col];
#pragma unroll
    for (int fm = 0; fm < 8; fm++) {
      const int row0 = m0 + wm * 128 + fm * 16 + lg * 4;
      if (EPI == 2) {
#pragma unroll
        for (int r = 0; r < 4; r++)
          ((unsigned short*)Cout)[(size_t)(row0 + r) * N + col] =
              f2bf(fmaxf(acc[fm][fn][r] + bv, 0.0f));
      } else {  // EPI 4: QKV split
        if (col < 2048) {
#pragma unroll
          for (int r = 0; r < 4; r++)
            ((unsigned short*)Cout)[(size_t)(row0 + r) * 2048 + col] =
                f2bf(acc[fm][fn][r]);
        } else {
          ushort4 ov;
          ov.x = f2bf(acc[fm][fn][0]);
          ov.y = f2bf(acc[fm][fn][1]);
          ov.z = f2bf(acc[fm][fn][2]);
          ov.w = f2bf(acc[fm][fn][3]);
          *(ushort4*)((unsigned short*)Cout2 + (size_t)(col - 2048) * 4096 + row0) = ov;
        }
      }
    }
  }
}

// ---------------------------------------------------------------------------
// Flash attention (causal), swapped-operand, LDS-staged K/V, double-buffered.
// (unchanged)
// ---------------------------------------------------------------------------
__global__ __launch_bounds__(256) void attn_kernel(
    const unsigned short* __restrict__ qk, const unsigned short* __restrict__ vT,
    unsigned short* __restrict__ o) {
  const int T = 2048, C = 1024, QKS = 2048;
  const int tid = threadIdx.x;
  const int wave = tid >> 6, lane = tid & 63;
  const int lr = lane & 15, lg = lane >> 4;
  const int b = blockIdx.y >> 4, hh = blockIdx.y & 15;
  const size_t rowb = (size_t)b * T * QKS;
  const int qcol = hh * 64;
  const int kcol = 1024 + hh * 64;
  const int vrow0 = hh * 64;
  const size_t bT = (size_t)b * T;
  const int swe = (lr & 7) << 3;

  __shared__ __align__(16) unsigned short Ks[2][64 * 64];
  __shared__ __align__(16) unsigned short Vs[2][64 * 64];
  __shared__ __align__(16) unsigned short Ps[4][16][72];

  const int rw = tid >> 3;
  const int c8 = ((tid & 7) ^ (rw & 7)) << 3;

#pragma unroll 1
  for (int pass = 0; pass < 2; ++pass) {
    const int qt = (pass == 0) ? (int)blockIdx.x : (31 - (int)blockIdx.x);
    const int qbase = qt * 64 + wave * 16;
    const int trow = qbase + lr;

    U8 qf[2];
#pragma unroll
    for (int j = 0; j < 2; j++)
      qf[j].v = *(const bf16x8*)(qk + rowb + (size_t)trow * QKS + qcol + j * 32 + lg * 8);
    asm volatile("s_waitcnt vmcnt(0)" ::: "memory");

    async16(qk + rowb + (size_t)rw * QKS + kcol + c8, Ks[0] + tid * 8);
    async16(qk + rowb + (size_t)(32 + rw) * QKS + kcol + c8, Ks[0] + 2048 + tid * 8);
    async16(vT + (size_t)(vrow0 + rw) * 4096 + bT + c8, Vs[0] + tid * 8);
    async16(vT + (size_t)(vrow0 + 32 + rw) * 4096 + bT + c8, Vs[0] + 2048 + tid * 8);

    f32x4 oa[4] = {};
    float mrun = -1e30f, lsum = 0.0f;
    int cur = 0;

    for (int sb = 0; sb <= qt; ++sb) {
      if (sb < qt) {
        const int s1 = (sb + 1) * 64;
        const int nb = cur ^ 1;
        async16(qk + rowb + (size_t)(s1 + rw) * QKS + kcol + c8, Ks[nb] + tid * 8);
        async16(qk + rowb + (size_t)(s1 + 32 + rw) * QKS + kcol + c8, Ks[nb] + 2048 + tid * 8);
        async16(vT + (size_t)(vrow0 + rw) * 4096 + bT + s1 + c8, Vs[nb] + tid * 8);
        async16(vT + (size_t)(vrow0 + 32 + rw) * 4096 + bT + s1 + c8, Vs[nb] + 2048 + tid * 8);
        asm volatile("s_waitcnt vmcnt(4)" ::: "memory");
      } else {
        asm volatile("s_waitcnt vmcnt(0)" ::: "memory");
      }
      block_barrier();

      const unsigned short* Kc = Ks[cur];
      const unsigned short* Vc = Vs[cur];
      const int s0 = sb * 64;

      f32x4 sa[4] = {};
#pragma unroll
      for (int j = 0; j < 2; j++) {
#pragma unroll
        for (int mf = 0; mf < 4; mf++) {
          U8 kf;
          kf.v = *(const bf16x8*)(Kc + (mf * 16 + lr) * 64 + ((j * 32 + lg * 8) ^ swe));
          sa[mf] = __builtin_amdgcn_mfma_f32_16x16x32_bf16(kf.v, qf[j].v, sa[mf], 0, 0, 0);
        }
      }
      float sv[16];
#pragma unroll
      for (int mf = 0; mf < 4; mf++)
#pragma unroll
        for (int r = 0; r < 4; r++) sv[mf * 4 + r] = sa[mf][r] * 0.125f;

      if (sb == qt) {
#pragma unroll
        for (int mf = 0; mf < 4; mf++)
#pragma unroll
          for (int r = 0; r < 4; r++)
            if (s0 + mf * 16 + lg * 4 + r > trow) sv[mf * 4 + r] = -1e30f;
      }

      float tm = sv[0];
#pragma unroll
      for (int i = 1; i < 16; i++) tm = fmaxf(tm, sv[i]);
      tm = fmaxf(tm, __shfl_xor(tm, 16));
      tm = fmaxf(tm, __shfl_xor(tm, 32));

      if (!__all(tm <= mrun + 8.0f)) {
        const float mn = fmaxf(mrun, tm);
        const float corr = __expf(mrun - mn);
        lsum *= corr;
#pragma unroll
        for (int c = 0; c < 4; c++)
#pragma unroll
          for (int r = 0; r < 4; r++) oa[c][r] *= corr;
        mrun = mn;
      }

      float rs = 0.0f;
#pragma unroll
      for (int i = 0; i < 16; i++) {
        sv[i] = __expf(sv[i] - mrun);
        rs += sv[i];
      }
      rs += __shfl_xor(rs, 16);
      rs += __shfl_xor(rs, 32);
      lsum += rs;

#pragma unroll
      for (int mf = 0; mf < 4; mf++) {
        ushort4 w;
        w.x = f2bf(sv[mf * 4 + 0]);
        w.y = f2bf(sv[mf * 4 + 1]);
        w.z = f2bf(sv[mf * 4 + 2]);
        w.w = f2bf(sv[mf * 4 + 3]);
        *(ushort4*)&Ps[wave][lr][mf * 16 + lg * 4] = w;
      }
      asm volatile("" ::: "memory");
      U8 pb[2];
      pb[0].v = *(const bf16x8*)&Ps[wave][lr][lg * 8];
      pb[1].v = *(const bf16x8*)&Ps[wave][lr][32 + lg * 8];
      asm volatile("" ::: "memory");

#pragma unroll
      for (int c = 0; c < 4; c++) {
#pragma unroll
        for (int ks = 0; ks < 2; ks++) {
          U8 vf;
          vf.v = *(const bf16x8*)(Vc + (c * 16 + lr) * 64 + ((ks * 32 + lg * 8) ^ swe));
          oa[c] = __builtin_amdgcn_mfma_f32_16x16x32_bf16(vf.v, pb[ks].v, oa[c], 0, 0, 0);
        }
      }

      block_barrier();
      cur ^= 1;
    }

    const float inv = 1.0f / lsum;
#pragma unroll
    for (int c = 0; c < 4; c++) {
      ushort4 ov;
      ov.x = f2bf(oa[c][0] * inv);
      ov.y = f2bf(oa[c][1] * inv);
      ov.z = f2bf(oa[c][2] * inv);
      ov.w = f2bf(oa[c][3] * inv);
      *(ushort4*)(o + (size_t)(bT + trow) * C + hh * 64 + c * 16 + lg * 4) = ov;
    }
  }
}

// ---------------------------------------------------------------------------
// Orchestration.  Workspace lifetime plan (80 MB):
//   0-6   WqkvT (dead after QKV)      | 16-24 W2T (needed thru FFN2 main)
//   6-8   WpT   (dead after proj)     | 24-32 h (dead after QKV)
//   8-16  W1T   (dead after FFN1)     | 32-48 qkb, 48-56 vTb (dead after attn)
//   56-64 att (dead after proj main) -> then h2
//   24-56 proj partials (2x16MB)     -> then ff1 (32MB)
//   x1 lives in d_out (16MB);  FFN2 partials: 64-80 (P0) + 0-16 (P1)
// ---------------------------------------------------------------------------
extern "C" void kernel_launch(void* const* d_in, const int* in_sizes, int n_in,
                              void* d_out, int out_size, void* d_ws, size_t ws_size,
                              hipStream_t stream) {
  (void)in_sizes; (void)n_in; (void)out_size; (void)ws_size;
  const int T = 2048, C = 1024, M = 2 * T, C4 = 4 * C;

  const float* x     = (const float*)d_in[0];
  const float* Wq    = (const float*)d_in[1];
  const float* Wk    = (const float*)d_in[2];
  const float* Wv    = (const float*)d_in[3];
  const float* Wproj = (const float*)d_in[4];
  const float* bproj = (const float*)d_in[5];
  const float* W1    = (const float*)d_in[6];
  const float* b1    = (const float*)d_in[7];
  const float* W2    = (const float*)d_in[8];
  const float* b2    = (const float*)d_in[9];
  const float* ln1g  = (const float*)d_in[10];
  const float* ln1b  = (const float*)d_in[11];
  const float* ln2g  = (const float*)d_in[12];
  const float* ln2b  = (const float*)d_in[13];
  float* out = (float*)d_out;

  char* ws = (char*)d_ws;
  const size_t MBy = (size_t)1 << 20;
  unsigned short* WqkvT = (unsigned short*)(ws + 0 * MBy);
  unsigned short* WqT = WqkvT;
  unsigned short* WkT = WqkvT + 1024 * 1024;
  unsigned short* WvT = WqkvT + 2048 * 1024;
  unsigned short* WpT = (unsigned short*)(ws + 6 * MBy);
  unsigned short* W1T = (unsigned short*)(ws + 8 * MBy);
  unsigned short* W2T = (unsigned short*)(ws + 16 * MBy);
  unsigned short* h   = (unsigned short*)(ws + 24 * MBy);
  unsigned short* qkb = (unsigned short*)(ws + 32 * MBy);
  unsigned short* vTb = (unsigned short*)(ws + 48 * MBy);
  unsigned short* att = (unsigned short*)(ws + 56 * MBy);
  float* projP0 = (float*)(ws + 24 * MBy);   // 16 MB (h/qkb region, dead)
  float* projP1 = (float*)(ws + 40 * MBy);   // 16 MB (qkb/vTb region, dead)
  float* x1     = out;                        // x1 lives in d_out
  unsigned short* h2  = att;                  // att dead after proj main
  unsigned short* ff1 = h;                    // 24-56, proj partials dead
  float* ffP0 = (float*)(ws + 64 * MBy);      // 16 MB (old x1 slot, free)
  float* ffP1 = (float*)(ws + 0 * MBy);       // 16 MB (WqkvT/WpT/W1T dead)

  const dim3 tb(32, 8);
  transpose_w<<<dim3(2, 32, 16), tb, 0, stream>>>(Wq, WqT, 1024, 64);
  transpose_w<<<dim3(2, 32, 16), tb, 0, stream>>>(Wk, WkT, 1024, 64);
  transpose_w<<<dim3(2, 32, 16), tb, 0, stream>>>(Wv, WvT, 1024, 64);
  transpose_w<<<dim3(32, 32, 1), tb, 0, stream>>>(Wproj, WpT, 1024, 1024);
  transpose_w<<<dim3(128, 32, 1), tb, 0, stream>>>(W1, W1T, 1024, 4096);
  transpose_w<<<dim3(32, 128, 1), tb, 0, stream>>>(W2, W2T, 4096, 1024);

  ln_kernel<<<M, 256, 0, stream>>>(x, ln1g, ln1b, h);

  // Fused QKV (8-phase 256^2): N=3072; cols<2048 -> qkb, cols>=2048 -> vTb^T
  gemm8p<4><<<192, 512, 0, stream>>>(h, WqkvT, qkb, vTb, nullptr, M, 3072, C);

  attn_kernel<<<dim3(16, 32), 256, 0, stream>>>(qkb, vTb, att);

  // proj: split-K=2 partials then fused reduce (+bproj +x) -> x1 (in d_out)
  gemm_sk<<<1024, 256, 0, stream>>>(att, WpT, projP0, projP1, M, C, C);
  reduce_add<<<2048, 256, 0, stream>>>(projP0, projP1, bproj, x, x1, M * C / 4);

  ln_kernel<<<M, 256, 0, stream>>>(x1, ln2g, ln2b, h2);

  // FFN1 (8-phase 256^2): relu(h2 @ W1 + b1) -> bf16
  gemm8p<2><<<256, 512, 0, stream>>>(h2, W1T, ff1, nullptr, b1, M, C4, C);

  // FFN2: split-K=2 partials then fused reduce (+b2 +x1) -> out (in place)
  gemm_sk<<<1024, 256, 0, stream>>>(ff1, W2T, ffP0, ffP1, M, C, C4);
  reduce_add<<<2048, 256, 0, stream>>>(ffP0, ffP1, b2, x1, out, M * C / 4);
}

// Round 9
// 243.545 us; speedup vs baseline: 1.6054x; 1.1196x over previous
//
#include <hip/hip_runtime.h>

// ---------------------------------------------------------------------------
// Types / helpers
// ---------------------------------------------------------------------------
typedef __bf16 bf16x8 __attribute__((ext_vector_type(8)));
typedef float  f32x4  __attribute__((ext_vector_type(4)));

union U8 { bf16x8 v; __bf16 e[8]; unsigned short u[8]; };

// Native HW conversion (v_cvt_pk_bf16_f32), RNE — replaces 4-op bit-twiddle.
__device__ __forceinline__ unsigned short f2bf(float f) {
  union { __bf16 b; unsigned short u; } c;
  c.b = (__bf16)f;
  return c.u;
}

__device__ __forceinline__ void async16(const void* g, void* l) {
  __builtin_amdgcn_global_load_lds(
      (__attribute__((address_space(1))) void*)(g),
      (__attribute__((address_space(3))) void*)(l), 16, 0, 0);
}

__device__ __forceinline__ void block_barrier() {
  asm volatile("" ::: "memory");
  __builtin_amdgcn_sched_barrier(0);
  __builtin_amdgcn_s_barrier();
  __builtin_amdgcn_sched_barrier(0);
  asm volatile("" ::: "memory");
}

// ---------------------------------------------------------------------------
// Batched transpose: in fp32 [batch][R][Cc] -> out bf16 [batch*Cc + c][R]
// ---------------------------------------------------------------------------
__global__ __launch_bounds__(256) void transpose_w(
    const float* __restrict__ in, unsigned short* __restrict__ out,
    int R, int Cc) {
  __shared__ float tile[32][33];
  const int batch = blockIdx.z;
  const float* ip = in + (size_t)batch * R * Cc;
  unsigned short* op = out + (size_t)batch * R * Cc;
  const int c0 = blockIdx.x * 32, r0 = blockIdx.y * 32;
  const int tx = threadIdx.x, ty = threadIdx.y;  // 32 x 8
#pragma unroll
  for (int i = 0; i < 32; i += 8)
    tile[ty + i][tx] = ip[(size_t)(r0 + ty + i) * Cc + c0 + tx];
  __syncthreads();
#pragma unroll
  for (int i = 0; i < 32; i += 8)
    op[(size_t)(c0 + ty + i) * R + r0 + tx] = f2bf(tile[tx][ty + i]);
}

// ---------------------------------------------------------------------------
// LayerNorm over rows of 1024, fp32 in -> bf16 out.
// ---------------------------------------------------------------------------
__global__ __launch_bounds__(256) void ln_kernel(
    const float* __restrict__ x, const float* __restrict__ g,
    const float* __restrict__ bta, unsigned short* __restrict__ out) {
  const int C = 1024;
  const int row = blockIdx.x, tid = threadIdx.x;
  const float4 v = ((const float4*)(x + (size_t)row * C))[tid];
  float s  = v.x + v.y + v.z + v.w;
  float ss = v.x * v.x + v.y * v.y + v.z * v.z + v.w * v.w;
#pragma unroll
  for (int off = 32; off > 0; off >>= 1) {
    s  += __shfl_down(s, off);
    ss += __shfl_down(ss, off);
  }
  __shared__ float r0[4], r1[4];
  const int wave = tid >> 6, lane = tid & 63;
  if (lane == 0) { r0[wave] = s; r1[wave] = ss; }
  __syncthreads();
  s  = r0[0] + r0[1] + r0[2] + r0[3];
  ss = r1[0] + r1[1] + r1[2] + r1[3];
  const float mu   = s * (1.0f / C);
  const float var  = ss * (1.0f / C) - mu * mu;
  const float rstd = rsqrtf(var + 1e-5f);
  const float4 gv = ((const float4*)g)[tid];
  const float4 bv = ((const float4*)bta)[tid];
  ushort4 o;
  o.x = f2bf((v.x - mu) * rstd * gv.x + bv.x);
  o.y = f2bf((v.y - mu) * rstd * gv.y + bv.y);
  o.z = f2bf((v.z - mu) * rstd * gv.z + bv.z);
  o.w = f2bf((v.w - mu) * rstd * gv.w + bv.w);
  ((ushort4*)(out + (size_t)row * C))[tid] = o;
}

// ---------------------------------------------------------------------------
// 128x64-tile latency GEMM (round-6 verified, 63us FFN2 / less for proj):
// 512 blocks = 2 blocks/CU. C = A*BT^T + bias + resid -> fp32. BK=64,
// triple-buffered 72 KB LDS, 2-tiles-ahead prefetch, counted vmcnt(6),
// chunk-XOR swizzle via pre-swizzled global source (0 conflicts verified).
// ---------------------------------------------------------------------------
__global__ __launch_bounds__(256, 2) void gemm_lat2(
    const unsigned short* __restrict__ A, const unsigned short* __restrict__ BT,
    float* __restrict__ Cout, const float* __restrict__ bias,
    const float* __restrict__ resid, int M, int N, int K) {
  __shared__ __align__(16) unsigned short As[3][8192];
  __shared__ __align__(16) unsigned short Bs[3][4096];
  const int tid = threadIdx.x;
  const int lane = tid & 63, wave = tid >> 6;
  const int wm = wave >> 1, wn = wave & 1;
  const int lr = lane & 15, lg = lane >> 4;

  const int nwg = gridDim.x;
  const int cpx = nwg >> 3;
  const int swz = ((int)blockIdx.x & 7) * cpx + ((int)blockIdx.x >> 3);
  const int Nt = N >> 6;
  const int g4 = swz / (4 * Nt);
  const int rem = swz - g4 * 4 * Nt;
  const int m0 = (g4 * 4 + (rem & 3)) << 7;
  const int n0 = (rem >> 2) << 6;

  const int srow = tid >> 3;
  const int sc = ((tid & 7) ^ (srow & 7)) << 3;
  const unsigned short* Ag = A + (size_t)(m0 + srow) * K + sc;
  const unsigned short* Bg = BT + (size_t)(n0 + srow) * K + sc;
  const size_t rskip = (size_t)32 * K;

  f32x4 acc[4][2] = {};
  const int nkt = K >> 6;

#define STG(T, B)                                                          \
  {                                                                        \
    const int kt_ = (T) << 6;                                              \
    _Pragma("unroll")                                                      \
    for (int j = 0; j < 4; ++j)                                            \
      async16(Ag + kt_ + (size_t)j * rskip, &As[B][j * 2048 + tid * 8]);   \
    async16(Bg + kt_, &Bs[B][tid * 8]);                                    \
    async16(Bg + kt_ + rskip, &Bs[B][2048 + tid * 8]);                     \
  }

  STG(0, 0);
  STG(1, 1);

  for (int t = 0; t < nkt; ++t) {
    const int buf = t % 3;
    if (t + 1 < nkt) asm volatile("s_waitcnt vmcnt(6)" ::: "memory");
    else             asm volatile("s_waitcnt vmcnt(0)" ::: "memory");
    block_barrier();
    if (t + 2 < nkt) {
      int sb = buf + 2; if (sb >= 3) sb -= 3;
      STG(t + 2, sb);
    }
#pragma unroll
    for (int kh = 0; kh < 2; ++kh) {
      const int kc = ((kh * 4 + lg) ^ (lr & 7)) << 3;
      bf16x8 afr[4], bfr[2];
#pragma unroll
      for (int fm = 0; fm < 4; fm++)
        afr[fm] = *(const bf16x8*)&As[buf][(wm * 64 + fm * 16 + lr) * 64 + kc];
#pragma unroll
      for (int fn = 0; fn < 2; fn++)
        bfr[fn] = *(const bf16x8*)&Bs[buf][(wn * 32 + fn * 16 + lr) * 64 + kc];
#pragma unroll
      for (int fm = 0; fm < 4; fm++)
#pragma unroll
        for (int fn = 0; fn < 2; fn++)
          acc[fm][fn] = __builtin_amdgcn_mfma_f32_16x16x32_bf16(
              afr[fm], bfr[fn], acc[fm][fn], 0, 0, 0);
    }
  }
#undef STG

#pragma unroll
  for (int fn = 0; fn < 2; fn++) {
    const int col = n0 + wn * 32 + fn * 16 + lr;
    const float bv = bias[col];
#pragma unroll
    for (int fm = 0; fm < 4; fm++) {
      const int row0 = m0 + wm * 64 + fm * 16 + lg * 4;
#pragma unroll
      for (int r = 0; r < 4; r++) {
        const size_t idx = (size_t)(row0 + r) * N + col;
        Cout[idx] = acc[fm][fn][r] + bv + resid[idx];
      }
    }
  }
}

// ---------------------------------------------------------------------------
// Split-K reduce (4 planes bf16): out[i] = sum_p P[p][i] + bias + out[i].
// out aliases resid (same index in-place) -> safe, deterministic.
// ---------------------------------------------------------------------------
__global__ __launch_bounds__(256) void reduce_add4(
    const unsigned short* __restrict__ p01, const unsigned short* __restrict__ p23,
    const float* __restrict__ bias, float* __restrict__ out, int n4) {
  const int stride = gridDim.x * 256;
#define BF(u) __uint_as_float(((unsigned)(u)) << 16)
  for (int i = blockIdx.x * 256 + threadIdx.x; i < n4; i += stride) {
    const ushort4 a = ((const ushort4*)p01)[i];
    const ushort4 b = ((const ushort4*)p01)[i + n4];
    const ushort4 c = ((const ushort4*)p23)[i];
    const ushort4 d = ((const ushort4*)p23)[i + n4];
    const float4 r = ((const float4*)out)[i];
    const float4 bv = ((const float4*)bias)[i & 255];
    float4 o;
    o.x = (BF(a.x) + BF(b.x)) + (BF(c.x) + BF(d.x)) + r.x + bv.x;
    o.y = (BF(a.y) + BF(b.y)) + (BF(c.y) + BF(d.y)) + r.y + bv.y;
    o.z = (BF(a.z) + BF(b.z)) + (BF(c.z) + BF(d.z)) + r.z + bv.z;
    o.w = (BF(a.w) + BF(b.w)) + (BF(c.w) + BF(d.w)) + r.w + bv.w;
    ((float4*)out)[i] = o;
  }
#undef BF
}

// ---------------------------------------------------------------------------
// 256x256 8-phase deep-pipelined GEMM, optional split-K.
// EPI: 2 = relu(+bias) -> bf16 ; 4 = QKV split (Q cols pre-scaled by
//      0.125*log2e for exp2-domain softmax) ; 5 = bf16 partial planes
//      (plane ks: ks<2 -> Cout, ks>=2 -> Cout2; +(ks&1)*M*N).
// ---------------------------------------------------------------------------
template <int EPI, int SPLITK>
__global__ __launch_bounds__(512, 2) void gemm8p(
    const unsigned short* __restrict__ A, const unsigned short* __restrict__ BT,
    void* __restrict__ Cout, void* __restrict__ Cout2,
    const float* __restrict__ bias, int M, int N, int K) {
  __shared__ __align__(16) unsigned short As[2][2][8192];
  __shared__ __align__(16) unsigned short Bs[2][2][8192];
  const int tid = threadIdx.x;
  const int lane = tid & 63;
  const int wave = tid >> 6;
  const int wm = wave >> 2, wn = wave & 3;  // 2 x 4 wave grid
  const int lr = lane & 15, lg = lane >> 4;

  const int nwg = gridDim.x;
  const int cpx = nwg >> 3;
  const int swz = ((int)blockIdx.x & 7) * cpx + ((int)blockIdx.x >> 3);
  int tile = swz, ks = 0;
  if (SPLITK > 1) {
    const int tilesPer = nwg / SPLITK;
    ks = swz / tilesPer;
    tile = swz - ks * tilesPer;
  }
  const int Ksl = K / SPLITK;
  const int k0 = ks * Ksl;
  const int Nt = N >> 8;
  const int g4 = tile / (4 * Nt);
  const int rem = tile - g4 * 4 * Nt;
  const int m0 = (g4 * 4 + (rem & 3)) << 8;
  const int n0 = (rem >> 2) << 8;

  const int srow = tid >> 2;
  const int scg = ((tid & 3) ^ ((srow >> 1) & 3)) << 3;
  const unsigned short* Ag = A + (size_t)(m0 + srow) * K + k0 + scg;
  const unsigned short* Bg = BT + (size_t)(n0 + srow) * K + k0 + scg;
  const size_t rskip = (size_t)128 * K;
  const int l8 = tid * 8;

  const int kch = (lg ^ ((lr >> 1) & 3)) << 3;

  f32x4 acc[8][4] = {};
  bf16x8 afr[4], bfr[4];
  const int nkt = Ksl >> 6;

  async16(Ag, &As[0][0][l8]);            async16(Ag + rskip, &As[0][0][l8 + 4096]);
  async16(Bg, &Bs[0][0][l8]);            async16(Bg + rskip, &Bs[0][0][l8 + 4096]);
  async16(Ag + 32, &As[0][1][l8]);       async16(Ag + 32 + rskip, &As[0][1][l8 + 4096]);
  async16(Bg + 32, &Bs[0][1][l8]);       async16(Bg + 32 + rskip, &Bs[0][1][l8 + 4096]);
  async16(Ag + 64, &As[1][0][l8]);       async16(Ag + 64 + rskip, &As[1][0][l8 + 4096]);
  async16(Bg + 64, &Bs[1][0][l8]);       async16(Bg + 64 + rskip, &Bs[1][0][l8 + 4096]);
  asm volatile("s_waitcnt vmcnt(4)" ::: "memory");
  block_barrier();

  for (int t = 0; t < nkt; ++t) {
    const int buf = t & 1, nbuf = buf ^ 1;
    const int kt1 = (t + 1) << 6, kt2 = (t + 2) << 6;
    const bool s1 = (t + 1 < nkt), s2 = (t + 2 < nkt);

    // ---- phase 1: ks=0, mh=0 ----
#pragma unroll
    for (int fm = 0; fm < 4; fm++)
      afr[fm] = *(const bf16x8*)&As[buf][0][(wm * 128 + fm * 16 + lr) * 32 + kch];
#pragma unroll
    for (int fn = 0; fn < 4; fn++)
      bfr[fn] = *(const bf16x8*)&Bs[buf][0][(wn * 64 + fn * 16 + lr) * 32 + kch];
    if (s1) {
      async16(Ag + kt1 + 32, &As[nbuf][1][l8]);
      async16(Ag + kt1 + 32 + rskip, &As[nbuf][1][l8 + 4096]);
    }
    block_barrier();
    __builtin_amdgcn_s_setprio(1);
#pragma unroll
    for (int fm = 0; fm < 4; fm++)
#pragma unroll
      for (int fn = 0; fn < 4; fn++)
        acc[fm][fn] = __builtin_amdgcn_mfma_f32_16x16x32_bf16(afr[fm], bfr[fn], acc[fm][fn], 0, 0, 0);
    __builtin_amdgcn_s_setprio(0);
    block_barrier();

    // ---- phase 2: ks=0, mh=1 ----
#pragma unroll
    for (int fm = 0; fm < 4; fm++)
      afr[fm] = *(const bf16x8*)&As[buf][0][(wm * 128 + 64 + fm * 16 + lr) * 32 + kch];
    if (s1) {
      async16(Bg + kt1 + 32, &Bs[nbuf][1][l8]);
      async16(Bg + kt1 + 32 + rskip, &Bs[nbuf][1][l8 + 4096]);
    }
    block_barrier();
    __builtin_amdgcn_s_setprio(1);
#pragma unroll
    for (int fm = 0; fm < 4; fm++)
#pragma unroll
      for (int fn = 0; fn < 4; fn++)
        acc[4 + fm][fn] = __builtin_amdgcn_mfma_f32_16x16x32_bf16(afr[fm], bfr[fn], acc[4 + fm][fn], 0, 0, 0);
    __builtin_amdgcn_s_setprio(0);
    block_barrier();

    // ---- phase 3: ks=1, mh=0 ----
#pragma unroll
    for (int fm = 0; fm < 4; fm++)
      afr[fm] = *(const bf16x8*)&As[buf][1][(wm * 128 + fm * 16 + lr) * 32 + kch];
#pragma unroll
    for (int fn = 0; fn < 4; fn++)
      bfr[fn] = *(const bf16x8*)&Bs[buf][1][(wn * 64 + fn * 16 + lr) * 32 + kch];
    if (s2) {
      async16(Ag + kt2, &As[buf][0][l8]);
      async16(Ag + kt2 + rskip, &As[buf][0][l8 + 4096]);
    }
    block_barrier();
    __builtin_amdgcn_s_setprio(1);
#pragma unroll
    for (int fm = 0; fm < 4; fm++)
#pragma unroll
      for (int fn = 0; fn < 4; fn++)
        acc[fm][fn] = __builtin_amdgcn_mfma_f32_16x16x32_bf16(afr[fm], bfr[fn], acc[fm][fn], 0, 0, 0);
    __builtin_amdgcn_s_setprio(0);
    block_barrier();

    // ---- phase 4: ks=1, mh=1 ----
#pragma unroll
    for (int fm = 0; fm < 4; fm++)
      afr[fm] = *(const bf16x8*)&As[buf][1][(wm * 128 + 64 + fm * 16 + lr) * 32 + kch];
    if (s2) {
      async16(Bg + kt2, &Bs[buf][0][l8]);
      async16(Bg + kt2 + rskip, &Bs[buf][0][l8 + 4096]);
    }
    block_barrier();
    __builtin_amdgcn_s_setprio(1);
#pragma unroll
    for (int fm = 0; fm < 4; fm++)
#pragma unroll
      for (int fn = 0; fn < 4; fn++)
        acc[4 + fm][fn] = __builtin_amdgcn_mfma_f32_16x16x32_bf16(afr[fm], bfr[fn], acc[4 + fm][fn], 0, 0, 0);
    __builtin_amdgcn_s_setprio(0);
    if (s2) asm volatile("s_waitcnt vmcnt(4)" ::: "memory");
    else    asm volatile("s_waitcnt vmcnt(0)" ::: "memory");
    block_barrier();
  }

#pragma unroll
  for (int fn = 0; fn < 4; fn++) {
    const int col = n0 + wn * 64 + fn * 16 + lr;
    float bv = 0.0f;
    if (EPI == 2) bv = bias[col];
#pragma unroll
    for (int fm = 0; fm < 8; fm++) {
      const int row0 = m0 + wm * 128 + fm * 16 + lg * 4;
      if (EPI == 2) {
#pragma unroll
        for (int r = 0; r < 4; r++)
          ((unsigned short*)Cout)[(size_t)(row0 + r) * N + col] =
              f2bf(fmaxf(acc[fm][fn][r] + bv, 0.0f));
      } else if (EPI == 5) {
        unsigned short* P = (unsigned short*)(ks < 2 ? Cout : Cout2) +
                            (size_t)(ks & 1) * M * N;
#pragma unroll
        for (int r = 0; r < 4; r++)
          P[(size_t)(row0 + r) * N + col] = f2bf(acc[fm][fn][r]);
      } else {  // EPI 4: QKV split; Q cols scaled into exp2 domain
        if (col < 2048) {
#pragma unroll
          for (int r = 0; r < 4; r++) {
            float val = acc[fm][fn][r];
            if (col < 1024) val *= 0.18033688011112042f;  // 0.125 * log2(e)
            ((unsigned short*)Cout)[(size_t)(row0 + r) * 2048 + col] = f2bf(val);
          }
        } else {
          ushort4 ov;
          ov.x = f2bf(acc[fm][fn][0]);
          ov.y = f2bf(acc[fm][fn][1]);
          ov.z = f2bf(acc[fm][fn][2]);
          ov.w = f2bf(acc[fm][fn][3]);
          *(ushort4*)((unsigned short*)Cout2 + (size_t)(col - 2048) * 4096 + row0) = ov;
        }
      }
    }
  }
}

// ---------------------------------------------------------------------------
// Flash attention (causal), swapped-operand, LDS-staged K/V, double-buffered.
// exp2-domain softmax (Q pre-scaled by 0.125*log2e in QKV epilogue):
//   p = 2^(s2 - m2), m2 = running max in log2 units, defer-max THR=8.
// ---------------------------------------------------------------------------
__global__ __launch_bounds__(256) void attn_kernel(
    const unsigned short* __restrict__ qk, const unsigned short* __restrict__ vT,
    unsigned short* __restrict__ o) {
  const int T = 2048, C = 1024, QKS = 2048;
  const int tid = threadIdx.x;
  const int wave = tid >> 6, lane = tid & 63;
  const int lr = lane & 15, lg = lane >> 4;
  const int b = blockIdx.y >> 4, hh = blockIdx.y & 15;
  const size_t rowb = (size_t)b * T * QKS;
  const int qcol = hh * 64;
  const int kcol = 1024 + hh * 64;
  const int vrow0 = hh * 64;
  const size_t bT = (size_t)b * T;
  const int swe = (lr & 7) << 3;

  __shared__ __align__(16) unsigned short Ks[2][64 * 64];
  __shared__ __align__(16) unsigned short Vs[2][64 * 64];
  __shared__ __align__(16) unsigned short Ps[4][16][72];

  const int rw = tid >> 3;
  const int c8 = ((tid & 7) ^ (rw & 7)) << 3;

#pragma unroll 1
  for (int pass = 0; pass < 2; ++pass) {
    const int qt = (pass == 0) ? (int)blockIdx.x : (31 - (int)blockIdx.x);
    const int qbase = qt * 64 + wave * 16;
    const int trow = qbase + lr;

    U8 qf[2];
#pragma unroll
    for (int j = 0; j < 2; j++)
      qf[j].v = *(const bf16x8*)(qk + rowb + (size_t)trow * QKS + qcol + j * 32 + lg * 8);
    asm volatile("s_waitcnt vmcnt(0)" ::: "memory");

    async16(qk + rowb + (size_t)rw * QKS + kcol + c8, Ks[0] + tid * 8);
    async16(qk + rowb + (size_t)(32 + rw) * QKS + kcol + c8, Ks[0] + 2048 + tid * 8);
    async16(vT + (size_t)(vrow0 + rw) * 4096 + bT + c8, Vs[0] + tid * 8);
    async16(vT + (size_t)(vrow0 + 32 + rw) * 4096 + bT + c8, Vs[0] + 2048 + tid * 8);

    f32x4 oa[4] = {};
    float mrun = -1e30f, lsum = 0.0f;
    int cur = 0;

    for (int sb = 0; sb <= qt; ++sb) {
      if (sb < qt) {
        const int s1 = (sb + 1) * 64;
        const int nb = cur ^ 1;
        async16(qk + rowb + (size_t)(s1 + rw) * QKS + kcol + c8, Ks[nb] + tid * 8);
        async16(qk + rowb + (size_t)(s1 + 32 + rw) * QKS + kcol + c8, Ks[nb] + 2048 + tid * 8);
        async16(vT + (size_t)(vrow0 + rw) * 4096 + bT + s1 + c8, Vs[nb] + tid * 8);
        async16(vT + (size_t)(vrow0 + 32 + rw) * 4096 + bT + s1 + c8, Vs[nb] + 2048 + tid * 8);
        asm volatile("s_waitcnt vmcnt(4)" ::: "memory");
      } else {
        asm volatile("s_waitcnt vmcnt(0)" ::: "memory");
      }
      block_barrier();

      const unsigned short* Kc = Ks[cur];
      const unsigned short* Vc = Vs[cur];
      const int s0 = sb * 64;

      f32x4 sa[4] = {};
#pragma unroll
      for (int j = 0; j < 2; j++) {
#pragma unroll
        for (int mf = 0; mf < 4; mf++) {
          U8 kf;
          kf.v = *(const bf16x8*)(Kc + (mf * 16 + lr) * 64 + ((j * 32 + lg * 8) ^ swe));
          sa[mf] = __builtin_amdgcn_mfma_f32_16x16x32_bf16(kf.v, qf[j].v, sa[mf], 0, 0, 0);
        }
      }
      float sv[16];
#pragma unroll
      for (int mf = 0; mf < 4; mf++)
#pragma unroll
        for (int r = 0; r < 4; r++) sv[mf * 4 + r] = sa[mf][r];  // already log2-scaled

      if (sb == qt) {
#pragma unroll
        for (int mf = 0; mf < 4; mf++)
#pragma unroll
          for (int r = 0; r < 4; r++)
            if (s0 + mf * 16 + lg * 4 + r > trow) sv[mf * 4 + r] = -1e30f;
      }

      // ILP-tree max over 16 lane-local values, then 2 cross-lane steps
      float t8[8];
#pragma unroll
      for (int i = 0; i < 8; i++) t8[i] = fmaxf(sv[i], sv[i + 8]);
#pragma unroll
      for (int i = 0; i < 4; i++) t8[i] = fmaxf(t8[i], t8[i + 4]);
      float tm = fmaxf(fmaxf(t8[0], t8[1]), fmaxf(t8[2], t8[3]));
      tm = fmaxf(tm, __shfl_xor(tm, 16));
      tm = fmaxf(tm, __shfl_xor(tm, 32));

      if (!__all(tm <= mrun + 8.0f)) {  // defer-max (log2 units)
        const float mn = fmaxf(mrun, tm);
        const float corr = __builtin_amdgcn_exp2f(mrun - mn);
        lsum *= corr;
#pragma unroll
        for (int c = 0; c < 4; c++)
#pragma unroll
          for (int r = 0; r < 4; r++) oa[c][r] *= corr;
        mrun = mn;
      }

#pragma unroll
      for (int i = 0; i < 16; i++)
        sv[i] = __builtin_amdgcn_exp2f(sv[i] - mrun);
      float s8[8];
#pragma unroll
      for (int i = 0; i < 8; i++) s8[i] = sv[i] + sv[i + 8];
#pragma unroll
      for (int i = 0; i < 4; i++) s8[i] = s8[i] + s8[i + 4];
      float rs = (s8[0] + s8[1]) + (s8[2] + s8[3]);
      rs += __shfl_xor(rs, 16);
      rs += __shfl_xor(rs, 32);
      lsum += rs;

#pragma unroll
      for (int mf = 0; mf < 4; mf++) {
        ushort4 w;
        w.x = f2bf(sv[mf * 4 + 0]);
        w.y = f2bf(sv[mf * 4 + 1]);
        w.z = f2bf(sv[mf * 4 + 2]);
        w.w = f2bf(sv[mf * 4 + 3]);
        *(ushort4*)&Ps[wave][lr][mf * 16 + lg * 4] = w;
      }
      asm volatile("" ::: "memory");
      U8 pb[2];
      pb[0].v = *(const bf16x8*)&Ps[wave][lr][lg * 8];
      pb[1].v = *(const bf16x8*)&Ps[wave][lr][32 + lg * 8];
      asm volatile("" ::: "memory");

#pragma unroll
      for (int c = 0; c < 4; c++) {
#pragma unroll
        for (int ks = 0; ks < 2; ks++) {
          U8 vf;
          vf.v = *(const bf16x8*)(Vc + (c * 16 + lr) * 64 + ((ks * 32 + lg * 8) ^ swe));
          oa[c] = __builtin_amdgcn_mfma_f32_16x16x32_bf16(vf.v, pb[ks].v, oa[c], 0, 0, 0);
        }
      }

      block_barrier();
      cur ^= 1;
    }

    const float inv = 1.0f / lsum;
#pragma unroll
    for (int c = 0; c < 4; c++) {
      ushort4 ov;
      ov.x = f2bf(oa[c][0] * inv);
      ov.y = f2bf(oa[c][1] * inv);
      ov.z = f2bf(oa[c][2] * inv);
      ov.w = f2bf(oa[c][3] * inv);
      *(ushort4*)(o + (size_t)(bT + trow) * C + hh * 64 + c * 16 + lg * 4) = ov;
    }
  }
}

// ---------------------------------------------------------------------------
// Orchestration.  Workspace lifetimes (80 MB):
//   0-6 WqkvT (dead after QKV) | 6-8 WpT (dead after proj) | 8-16 W1T (dead
//   after FFN1) | 16-24 W2T (thru FFN2) | 24-32 h (dead after QKV) |
//   32-48 qkb, 48-56 vTb (dead after attn) | 56-64 att -> h2 (dead after
//   FFN1) | 24-56 ff1 after FFN1 | x1 = d_out | FFN2 bf16 partials:
//   planes 0,1 @ 0-16 MB; planes 2,3 @ 64-80 MB.
// ---------------------------------------------------------------------------
extern "C" void kernel_launch(void* const* d_in, const int* in_sizes, int n_in,
                              void* d_out, int out_size, void* d_ws, size_t ws_size,
                              hipStream_t stream) {
  (void)in_sizes; (void)n_in; (void)out_size; (void)ws_size;
  const int T = 2048, C = 1024, M = 2 * T, C4 = 4 * C;

  const float* x     = (const float*)d_in[0];
  const float* Wq    = (const float*)d_in[1];
  const float* Wk    = (const float*)d_in[2];
  const float* Wv    = (const float*)d_in[3];
  const float* Wproj = (const float*)d_in[4];
  const float* bproj = (const float*)d_in[5];
  const float* W1    = (const float*)d_in[6];
  const float* b1    = (const float*)d_in[7];
  const float* W2    = (const float*)d_in[8];
  const float* b2    = (const float*)d_in[9];
  const float* ln1g  = (const float*)d_in[10];
  const float* ln1b  = (const float*)d_in[11];
  const float* ln2g  = (const float*)d_in[12];
  const float* ln2b  = (const float*)d_in[13];
  float* out = (float*)d_out;

  char* ws = (char*)d_ws;
  const size_t MBy = (size_t)1 << 20;
  unsigned short* WqkvT = (unsigned short*)(ws + 0 * MBy);
  unsigned short* WqT = WqkvT;
  unsigned short* WkT = WqkvT + 1024 * 1024;
  unsigned short* WvT = WqkvT + 2048 * 1024;
  unsigned short* WpT = (unsigned short*)(ws + 6 * MBy);
  unsigned short* W1T = (unsigned short*)(ws + 8 * MBy);
  unsigned short* W2T = (unsigned short*)(ws + 16 * MBy);
  unsigned short* h   = (unsigned short*)(ws + 24 * MBy);
  unsigned short* qkb = (unsigned short*)(ws + 32 * MBy);
  unsigned short* vTb = (unsigned short*)(ws + 48 * MBy);
  unsigned short* att = (unsigned short*)(ws + 56 * MBy);
  float* x1 = out;                                    // x1 lives in d_out
  unsigned short* h2  = att;                          // att dead after proj
  unsigned short* ff1 = h;                            // 24-56 after FFN1 frees
  unsigned short* ffP01 = (unsigned short*)(ws + 0 * MBy);   // planes 0,1
  unsigned short* ffP23 = (unsigned short*)(ws + 64 * MBy);  // planes 2,3

  const dim3 tb(32, 8);
  transpose_w<<<dim3(2, 32, 16), tb, 0, stream>>>(Wq, WqT, 1024, 64);
  transpose_w<<<dim3(2, 32, 16), tb, 0, stream>>>(Wk, WkT, 1024, 64);
  transpose_w<<<dim3(2, 32, 16), tb, 0, stream>>>(Wv, WvT, 1024, 64);
  transpose_w<<<dim3(32, 32, 1), tb, 0, stream>>>(Wproj, WpT, 1024, 1024);
  transpose_w<<<dim3(128, 32, 1), tb, 0, stream>>>(W1, W1T, 1024, 4096);
  transpose_w<<<dim3(32, 128, 1), tb, 0, stream>>>(W2, W2T, 4096, 1024);

  ln_kernel<<<M, 256, 0, stream>>>(x, ln1g, ln1b, h);

  // Fused QKV (8-phase 256^2): Q cols pre-scaled by 0.125*log2e
  gemm8p<4, 1><<<192, 512, 0, stream>>>(h, WqkvT, qkb, vTb, nullptr, M, 3072, C);

  attn_kernel<<<dim3(16, 32), 256, 0, stream>>>(qkb, vTb, att);

  // proj (+bproj +x) -> x1 (d_out), round-6 verified gemm_lat2
  gemm_lat2<<<512, 256, 0, stream>>>(att, WpT, x1, bproj, x, M, C, C);

  ln_kernel<<<M, 256, 0, stream>>>(x1, ln2g, ln2b, h2);

  // FFN1 (8-phase 256^2): relu(h2 @ W1 + b1) -> bf16
  gemm8p<2, 1><<<256, 512, 0, stream>>>(h2, W1T, ff1, nullptr, b1, M, C4, C);

  // FFN2: split-K=4 8-phase partials (bf16) + fused reduce (+b2 +x1 in-place)
  gemm8p<5, 4><<<256, 512, 0, stream>>>(ff1, W2T, ffP01, ffP23, nullptr, M, C, C4);
  reduce_add4<<<2048, 256, 0, stream>>>(ffP01, ffP23, b2, out, M * C / 4);
}

// Round 10
// 238.069 us; speedup vs baseline: 1.6423x; 1.0230x over previous
//
#include <hip/hip_runtime.h>

// ---------------------------------------------------------------------------
// Types / helpers
// ---------------------------------------------------------------------------
typedef __bf16 bf16x8 __attribute__((ext_vector_type(8)));
typedef float  f32x4  __attribute__((ext_vector_type(4)));

union U8 { bf16x8 v; __bf16 e[8]; unsigned short u[8]; };

// Native HW conversion (v_cvt_*_bf16), RNE.
__device__ __forceinline__ unsigned short f2bf(float f) {
  union { __bf16 b; unsigned short u; } c;
  c.b = (__bf16)f;
  return c.u;
}

__device__ __forceinline__ void async16(const void* g, void* l) {
  __builtin_amdgcn_global_load_lds(
      (__attribute__((address_space(1))) void*)(g),
      (__attribute__((address_space(3))) void*)(l), 16, 0, 0);
}

__device__ __forceinline__ void block_barrier() {
  asm volatile("" ::: "memory");
  __builtin_amdgcn_sched_barrier(0);
  __builtin_amdgcn_s_barrier();
  __builtin_amdgcn_sched_barrier(0);
  asm volatile("" ::: "memory");
}

// ---------------------------------------------------------------------------
// Batched transpose: in fp32 [batch][R][Cc] -> out bf16 [batch*Cc + c][R]
// ---------------------------------------------------------------------------
__global__ __launch_bounds__(256) void transpose_w(
    const float* __restrict__ in, unsigned short* __restrict__ out,
    int R, int Cc) {
  __shared__ float tile[32][33];
  const int batch = blockIdx.z;
  const float* ip = in + (size_t)batch * R * Cc;
  unsigned short* op = out + (size_t)batch * R * Cc;
  const int c0 = blockIdx.x * 32, r0 = blockIdx.y * 32;
  const int tx = threadIdx.x, ty = threadIdx.y;  // 32 x 8
#pragma unroll
  for (int i = 0; i < 32; i += 8)
    tile[ty + i][tx] = ip[(size_t)(r0 + ty + i) * Cc + c0 + tx];
  __syncthreads();
#pragma unroll
  for (int i = 0; i < 32; i += 8)
    op[(size_t)(c0 + ty + i) * R + r0 + tx] = f2bf(tile[tx][ty + i]);
}

// ---------------------------------------------------------------------------
// LayerNorm over rows of 1024, fp32 in -> bf16 out.
// ---------------------------------------------------------------------------
__global__ __launch_bounds__(256) void ln_kernel(
    const float* __restrict__ x, const float* __restrict__ g,
    const float* __restrict__ bta, unsigned short* __restrict__ out) {
  const int C = 1024;
  const int row = blockIdx.x, tid = threadIdx.x;
  const float4 v = ((const float4*)(x + (size_t)row * C))[tid];
  float s  = v.x + v.y + v.z + v.w;
  float ss = v.x * v.x + v.y * v.y + v.z * v.z + v.w * v.w;
#pragma unroll
  for (int off = 32; off > 0; off >>= 1) {
    s  += __shfl_down(s, off);
    ss += __shfl_down(ss, off);
  }
  __shared__ float r0[4], r1[4];
  const int wave = tid >> 6, lane = tid & 63;
  if (lane == 0) { r0[wave] = s; r1[wave] = ss; }
  __syncthreads();
  s  = r0[0] + r0[1] + r0[2] + r0[3];
  ss = r1[0] + r1[1] + r1[2] + r1[3];
  const float mu   = s * (1.0f / C);
  const float var  = ss * (1.0f / C) - mu * mu;
  const float rstd = rsqrtf(var + 1e-5f);
  const float4 gv = ((const float4*)g)[tid];
  const float4 bv = ((const float4*)bta)[tid];
  ushort4 o;
  o.x = f2bf((v.x - mu) * rstd * gv.x + bv.x);
  o.y = f2bf((v.y - mu) * rstd * gv.y + bv.y);
  o.z = f2bf((v.z - mu) * rstd * gv.z + bv.z);
  o.w = f2bf((v.w - mu) * rstd * gv.w + bv.w);
  ((ushort4*)(out + (size_t)row * C))[tid] = o;
}

// ---------------------------------------------------------------------------
// 128x64-tile latency GEMM (round-6 verified): 512 blocks = 2 blocks/CU.
// C = A*BT^T + bias + resid -> fp32. BK=64, triple-buffered 72 KB LDS,
// 2-tiles-ahead prefetch, counted vmcnt(6), chunk-XOR swizzle (0 conflicts).
// ---------------------------------------------------------------------------
__global__ __launch_bounds__(256, 2) void gemm_lat2(
    const unsigned short* __restrict__ A, const unsigned short* __restrict__ BT,
    float* __restrict__ Cout, const float* __restrict__ bias,
    const float* __restrict__ resid, int M, int N, int K) {
  __shared__ __align__(16) unsigned short As[3][8192];
  __shared__ __align__(16) unsigned short Bs[3][4096];
  const int tid = threadIdx.x;
  const int lane = tid & 63, wave = tid >> 6;
  const int wm = wave >> 1, wn = wave & 1;
  const int lr = lane & 15, lg = lane >> 4;

  const int nwg = gridDim.x;
  const int cpx = nwg >> 3;
  const int swz = ((int)blockIdx.x & 7) * cpx + ((int)blockIdx.x >> 3);
  const int Nt = N >> 6;
  const int g4 = swz / (4 * Nt);
  const int rem = swz - g4 * 4 * Nt;
  const int m0 = (g4 * 4 + (rem & 3)) << 7;
  const int n0 = (rem >> 2) << 6;

  const int srow = tid >> 3;
  const int sc = ((tid & 7) ^ (srow & 7)) << 3;
  const unsigned short* Ag = A + (size_t)(m0 + srow) * K + sc;
  const unsigned short* Bg = BT + (size_t)(n0 + srow) * K + sc;
  const size_t rskip = (size_t)32 * K;

  f32x4 acc[4][2] = {};
  const int nkt = K >> 6;

#define STG(T, B)                                                          \
  {                                                                        \
    const int kt_ = (T) << 6;                                              \
    _Pragma("unroll")                                                      \
    for (int j = 0; j < 4; ++j)                                            \
      async16(Ag + kt_ + (size_t)j * rskip, &As[B][j * 2048 + tid * 8]);   \
    async16(Bg + kt_, &Bs[B][tid * 8]);                                    \
    async16(Bg + kt_ + rskip, &Bs[B][2048 + tid * 8]);                     \
  }

  STG(0, 0);
  STG(1, 1);

  for (int t = 0; t < nkt; ++t) {
    const int buf = t % 3;
    if (t + 1 < nkt) asm volatile("s_waitcnt vmcnt(6)" ::: "memory");
    else             asm volatile("s_waitcnt vmcnt(0)" ::: "memory");
    block_barrier();
    if (t + 2 < nkt) {
      int sb = buf + 2; if (sb >= 3) sb -= 3;
      STG(t + 2, sb);
    }
#pragma unroll
    for (int kh = 0; kh < 2; ++kh) {
      const int kc = ((kh * 4 + lg) ^ (lr & 7)) << 3;
      bf16x8 afr[4], bfr[2];
#pragma unroll
      for (int fm = 0; fm < 4; fm++)
        afr[fm] = *(const bf16x8*)&As[buf][(wm * 64 + fm * 16 + lr) * 64 + kc];
#pragma unroll
      for (int fn = 0; fn < 2; fn++)
        bfr[fn] = *(const bf16x8*)&Bs[buf][(wn * 32 + fn * 16 + lr) * 64 + kc];
#pragma unroll
      for (int fm = 0; fm < 4; fm++)
#pragma unroll
        for (int fn = 0; fn < 2; fn++)
          acc[fm][fn] = __builtin_amdgcn_mfma_f32_16x16x32_bf16(
              afr[fm], bfr[fn], acc[fm][fn], 0, 0, 0);
    }
  }
#undef STG

#pragma unroll
  for (int fn = 0; fn < 2; fn++) {
    const int col = n0 + wn * 32 + fn * 16 + lr;
    const float bv = bias[col];
#pragma unroll
    for (int fm = 0; fm < 4; fm++) {
      const int row0 = m0 + wm * 64 + fm * 16 + lg * 4;
#pragma unroll
      for (int r = 0; r < 4; r++) {
        const size_t idx = (size_t)(row0 + r) * N + col;
        Cout[idx] = acc[fm][fn][r] + bv + resid[idx];
      }
    }
  }
}

// ---------------------------------------------------------------------------
// Split-K reduce (4 planes bf16): out[i] = sum_p P[p][i] + bias + out[i].
// ---------------------------------------------------------------------------
__global__ __launch_bounds__(256) void reduce_add4(
    const unsigned short* __restrict__ p01, const unsigned short* __restrict__ p23,
    const float* __restrict__ bias, float* __restrict__ out, int n4) {
  const int stride = gridDim.x * 256;
#define BF(u) __uint_as_float(((unsigned)(u)) << 16)
  for (int i = blockIdx.x * 256 + threadIdx.x; i < n4; i += stride) {
    const ushort4 a = ((const ushort4*)p01)[i];
    const ushort4 b = ((const ushort4*)p01)[i + n4];
    const ushort4 c = ((const ushort4*)p23)[i];
    const ushort4 d = ((const ushort4*)p23)[i + n4];
    const float4 r = ((const float4*)out)[i];
    const float4 bv = ((const float4*)bias)[i & 255];
    float4 o;
    o.x = (BF(a.x) + BF(b.x)) + (BF(c.x) + BF(d.x)) + r.x + bv.x;
    o.y = (BF(a.y) + BF(b.y)) + (BF(c.y) + BF(d.y)) + r.y + bv.y;
    o.z = (BF(a.z) + BF(b.z)) + (BF(c.z) + BF(d.z)) + r.z + bv.z;
    o.w = (BF(a.w) + BF(b.w)) + (BF(c.w) + BF(d.w)) + r.w + bv.w;
    ((float4*)out)[i] = o;
  }
#undef BF
}

// ---------------------------------------------------------------------------
// 256x256 8-phase deep-pipelined GEMM, optional split-K.
// EPI: 2 = relu(+bias) -> bf16 ; 4 = QKV split (Q cols pre-scaled by
//      0.125*log2e) ; 5 = bf16 partial planes.
// ---------------------------------------------------------------------------
template <int EPI, int SPLITK>
__global__ __launch_bounds__(512, 2) void gemm8p(
    const unsigned short* __restrict__ A, const unsigned short* __restrict__ BT,
    void* __restrict__ Cout, void* __restrict__ Cout2,
    const float* __restrict__ bias, int M, int N, int K) {
  __shared__ __align__(16) unsigned short As[2][2][8192];
  __shared__ __align__(16) unsigned short Bs[2][2][8192];
  const int tid = threadIdx.x;
  const int lane = tid & 63;
  const int wave = tid >> 6;
  const int wm = wave >> 2, wn = wave & 3;  // 2 x 4 wave grid
  const int lr = lane & 15, lg = lane >> 4;

  const int nwg = gridDim.x;
  const int cpx = nwg >> 3;
  const int swz = ((int)blockIdx.x & 7) * cpx + ((int)blockIdx.x >> 3);
  int tile = swz, ks = 0;
  if (SPLITK > 1) {
    const int tilesPer = nwg / SPLITK;
    ks = swz / tilesPer;
    tile = swz - ks * tilesPer;
  }
  const int Ksl = K / SPLITK;
  const int k0 = ks * Ksl;
  const int Nt = N >> 8;
  const int g4 = tile / (4 * Nt);
  const int rem = tile - g4 * 4 * Nt;
  const int m0 = (g4 * 4 + (rem & 3)) << 8;
  const int n0 = (rem >> 2) << 8;

  const int srow = tid >> 2;
  const int scg = ((tid & 3) ^ ((srow >> 1) & 3)) << 3;
  const unsigned short* Ag = A + (size_t)(m0 + srow) * K + k0 + scg;
  const unsigned short* Bg = BT + (size_t)(n0 + srow) * K + k0 + scg;
  const size_t rskip = (size_t)128 * K;
  const int l8 = tid * 8;

  const int kch = (lg ^ ((lr >> 1) & 3)) << 3;

  f32x4 acc[8][4] = {};
  bf16x8 afr[4], bfr[4];
  const int nkt = Ksl >> 6;

  async16(Ag, &As[0][0][l8]);            async16(Ag + rskip, &As[0][0][l8 + 4096]);
  async16(Bg, &Bs[0][0][l8]);            async16(Bg + rskip, &Bs[0][0][l8 + 4096]);
  async16(Ag + 32, &As[0][1][l8]);       async16(Ag + 32 + rskip, &As[0][1][l8 + 4096]);
  async16(Bg + 32, &Bs[0][1][l8]);       async16(Bg + 32 + rskip, &Bs[0][1][l8 + 4096]);
  async16(Ag + 64, &As[1][0][l8]);       async16(Ag + 64 + rskip, &As[1][0][l8 + 4096]);
  async16(Bg + 64, &Bs[1][0][l8]);       async16(Bg + 64 + rskip, &Bs[1][0][l8 + 4096]);
  asm volatile("s_waitcnt vmcnt(4)" ::: "memory");
  block_barrier();

  for (int t = 0; t < nkt; ++t) {
    const int buf = t & 1, nbuf = buf ^ 1;
    const int kt1 = (t + 1) << 6, kt2 = (t + 2) << 6;
    const bool s1 = (t + 1 < nkt), s2 = (t + 2 < nkt);

    // ---- phase 1: ks=0, mh=0 ----
#pragma unroll
    for (int fm = 0; fm < 4; fm++)
      afr[fm] = *(const bf16x8*)&As[buf][0][(wm * 128 + fm * 16 + lr) * 32 + kch];
#pragma unroll
    for (int fn = 0; fn < 4; fn++)
      bfr[fn] = *(const bf16x8*)&Bs[buf][0][(wn * 64 + fn * 16 + lr) * 32 + kch];
    if (s1) {
      async16(Ag + kt1 + 32, &As[nbuf][1][l8]);
      async16(Ag + kt1 + 32 + rskip, &As[nbuf][1][l8 + 4096]);
    }
    block_barrier();
    __builtin_amdgcn_s_setprio(1);
#pragma unroll
    for (int fm = 0; fm < 4; fm++)
#pragma unroll
      for (int fn = 0; fn < 4; fn++)
        acc[fm][fn] = __builtin_amdgcn_mfma_f32_16x16x32_bf16(afr[fm], bfr[fn], acc[fm][fn], 0, 0, 0);
    __builtin_amdgcn_s_setprio(0);
    block_barrier();

    // ---- phase 2: ks=0, mh=1 ----
#pragma unroll
    for (int fm = 0; fm < 4; fm++)
      afr[fm] = *(const bf16x8*)&As[buf][0][(wm * 128 + 64 + fm * 16 + lr) * 32 + kch];
    if (s1) {
      async16(Bg + kt1 + 32, &Bs[nbuf][1][l8]);
      async16(Bg + kt1 + 32 + rskip, &Bs[nbuf][1][l8 + 4096]);
    }
    block_barrier();
    __builtin_amdgcn_s_setprio(1);
#pragma unroll
    for (int fm = 0; fm < 4; fm++)
#pragma unroll
      for (int fn = 0; fn < 4; fn++)
        acc[4 + fm][fn] = __builtin_amdgcn_mfma_f32_16x16x32_bf16(afr[fm], bfr[fn], acc[4 + fm][fn], 0, 0, 0);
    __builtin_amdgcn_s_setprio(0);
    block_barrier();

    // ---- phase 3: ks=1, mh=0 ----
#pragma unroll
    for (int fm = 0; fm < 4; fm++)
      afr[fm] = *(const bf16x8*)&As[buf][1][(wm * 128 + fm * 16 + lr) * 32 + kch];
#pragma unroll
    for (int fn = 0; fn < 4; fn++)
      bfr[fn] = *(const bf16x8*)&Bs[buf][1][(wn * 64 + fn * 16 + lr) * 32 + kch];
    if (s2) {
      async16(Ag + kt2, &As[buf][0][l8]);
      async16(Ag + kt2 + rskip, &As[buf][0][l8 + 4096]);
    }
    block_barrier();
    __builtin_amdgcn_s_setprio(1);
#pragma unroll
    for (int fm = 0; fm < 4; fm++)
#pragma unroll
      for (int fn = 0; fn < 4; fn++)
        acc[fm][fn] = __builtin_amdgcn_mfma_f32_16x16x32_bf16(afr[fm], bfr[fn], acc[fm][fn], 0, 0, 0);
    __builtin_amdgcn_s_setprio(0);
    block_barrier();

    // ---- phase 4: ks=1, mh=1 ----
#pragma unroll
    for (int fm = 0; fm < 4; fm++)
      afr[fm] = *(const bf16x8*)&As[buf][1][(wm * 128 + 64 + fm * 16 + lr) * 32 + kch];
    if (s2) {
      async16(Bg + kt2, &Bs[buf][0][l8]);
      async16(Bg + kt2 + rskip, &Bs[buf][0][l8 + 4096]);
    }
    block_barrier();
    __builtin_amdgcn_s_setprio(1);
#pragma unroll
    for (int fm = 0; fm < 4; fm++)
#pragma unroll
      for (int fn = 0; fn < 4; fn++)
        acc[4 + fm][fn] = __builtin_amdgcn_mfma_f32_16x16x32_bf16(afr[fm], bfr[fn], acc[4 + fm][fn], 0, 0, 0);
    __builtin_amdgcn_s_setprio(0);
    if (s2) asm volatile("s_waitcnt vmcnt(4)" ::: "memory");
    else    asm volatile("s_waitcnt vmcnt(0)" ::: "memory");
    block_barrier();
  }

#pragma unroll
  for (int fn = 0; fn < 4; fn++) {
    const int col = n0 + wn * 64 + fn * 16 + lr;
    float bv = 0.0f;
    if (EPI == 2) bv = bias[col];
#pragma unroll
    for (int fm = 0; fm < 8; fm++) {
      const int row0 = m0 + wm * 128 + fm * 16 + lg * 4;
      if (EPI == 2) {
#pragma unroll
        for (int r = 0; r < 4; r++)
          ((unsigned short*)Cout)[(size_t)(row0 + r) * N + col] =
              f2bf(fmaxf(acc[fm][fn][r] + bv, 0.0f));
      } else if (EPI == 5) {
        unsigned short* P = (unsigned short*)(ks < 2 ? Cout : Cout2) +
                            (size_t)(ks & 1) * M * N;
#pragma unroll
        for (int r = 0; r < 4; r++)
          P[(size_t)(row0 + r) * N + col] = f2bf(acc[fm][fn][r]);
      } else {  // EPI 4: QKV split; Q cols scaled into exp2 domain
        if (col < 2048) {
#pragma unroll
          for (int r = 0; r < 4; r++) {
            float val = acc[fm][fn][r];
            if (col < 1024) val *= 0.18033688011112042f;  // 0.125 * log2(e)
            ((unsigned short*)Cout)[(size_t)(row0 + r) * 2048 + col] = f2bf(val);
          }
        } else {
          ushort4 ov;
          ov.x = f2bf(acc[fm][fn][0]);
          ov.y = f2bf(acc[fm][fn][1]);
          ov.z = f2bf(acc[fm][fn][2]);
          ov.w = f2bf(acc[fm][fn][3]);
          *(ushort4*)((unsigned short*)Cout2 + (size_t)(col - 2048) * 4096 + row0) = ov;
        }
      }
    }
  }
}

// ---------------------------------------------------------------------------
// Flash attention (causal), swapped-operand, LDS-staged K/V, double-buffered,
// exp2-domain softmax. XCD-grouped 1-D grid (512 blocks):
//   id = (bh&7) + 8*(qp + 16*(bh>>3))  =>  id%8 == bh&7
// so all 16 q-pair blocks of one (b,h) land on ONE XCD; its 4 bh values
// (2 MB K/V) fit the 4 MB per-XCD L2 -> kills the 121 MB cross-XCD re-fetch.
// ---------------------------------------------------------------------------
__global__ __launch_bounds__(256) void attn_kernel(
    const unsigned short* __restrict__ qk, const unsigned short* __restrict__ vT,
    unsigned short* __restrict__ o) {
  const int T = 2048, C = 1024, QKS = 2048;
  const int tid = threadIdx.x;
  const int wave = tid >> 6, lane = tid & 63;
  const int lr = lane & 15, lg = lane >> 4;

  // invert XCD-grouped mapping
  const int id = (int)blockIdx.x;
  const int rest = id >> 3;
  const int qp = rest & 15;
  const int bhv = ((rest >> 4) << 3) | (id & 7);
  const int b = bhv >> 4, hh = bhv & 15;

  const size_t rowb = (size_t)b * T * QKS;
  const int qcol = hh * 64;
  const int kcol = 1024 + hh * 64;
  const int vrow0 = hh * 64;
  const size_t bT = (size_t)b * T;
  const int swe = (lr & 7) << 3;

  __shared__ __align__(16) unsigned short Ks[2][64 * 64];
  __shared__ __align__(16) unsigned short Vs[2][64 * 64];
  __shared__ __align__(16) unsigned short Ps[4][16][72];

  const int rw = tid >> 3;
  const int c8 = ((tid & 7) ^ (rw & 7)) << 3;

#pragma unroll 1
  for (int pass = 0; pass < 2; ++pass) {
    const int qt = (pass == 0) ? qp : (31 - qp);
    const int qbase = qt * 64 + wave * 16;
    const int trow = qbase + lr;

    U8 qf[2];
#pragma unroll
    for (int j = 0; j < 2; j++)
      qf[j].v = *(const bf16x8*)(qk + rowb + (size_t)trow * QKS + qcol + j * 32 + lg * 8);
    asm volatile("s_waitcnt vmcnt(0)" ::: "memory");

    async16(qk + rowb + (size_t)rw * QKS + kcol + c8, Ks[0] + tid * 8);
    async16(qk + rowb + (size_t)(32 + rw) * QKS + kcol + c8, Ks[0] + 2048 + tid * 8);
    async16(vT + (size_t)(vrow0 + rw) * 4096 + bT + c8, Vs[0] + tid * 8);
    async16(vT + (size_t)(vrow0 + 32 + rw) * 4096 + bT + c8, Vs[0] + 2048 + tid * 8);

    f32x4 oa[4] = {};
    float mrun = -1e30f, lsum = 0.0f;
    int cur = 0;

    for (int sb = 0; sb <= qt; ++sb) {
      if (sb < qt) {
        const int s1 = (sb + 1) * 64;
        const int nb = cur ^ 1;
        async16(qk + rowb + (size_t)(s1 + rw) * QKS + kcol + c8, Ks[nb] + tid * 8);
        async16(qk + rowb + (size_t)(s1 + 32 + rw) * QKS + kcol + c8, Ks[nb] + 2048 + tid * 8);
        async16(vT + (size_t)(vrow0 + rw) * 4096 + bT + s1 + c8, Vs[nb] + tid * 8);
        async16(vT + (size_t)(vrow0 + 32 + rw) * 4096 + bT + s1 + c8, Vs[nb] + 2048 + tid * 8);
        asm volatile("s_waitcnt vmcnt(4)" ::: "memory");
      } else {
        asm volatile("s_waitcnt vmcnt(0)" ::: "memory");
      }
      block_barrier();

      const unsigned short* Kc = Ks[cur];
      const unsigned short* Vc = Vs[cur];
      const int s0 = sb * 64;

      f32x4 sa[4] = {};
#pragma unroll
      for (int j = 0; j < 2; j++) {
#pragma unroll
        for (int mf = 0; mf < 4; mf++) {
          U8 kf;
          kf.v = *(const bf16x8*)(Kc + (mf * 16 + lr) * 64 + ((j * 32 + lg * 8) ^ swe));
          sa[mf] = __builtin_amdgcn_mfma_f32_16x16x32_bf16(kf.v, qf[j].v, sa[mf], 0, 0, 0);
        }
      }
      float sv[16];
#pragma unroll
      for (int mf = 0; mf < 4; mf++)
#pragma unroll
        for (int r = 0; r < 4; r++) sv[mf * 4 + r] = sa[mf][r];  // log2-scaled

      if (sb == qt) {
#pragma unroll
        for (int mf = 0; mf < 4; mf++)
#pragma unroll
          for (int r = 0; r < 4; r++)
            if (s0 + mf * 16 + lg * 4 + r > trow) sv[mf * 4 + r] = -1e30f;
      }

      float t8[8];
#pragma unroll
      for (int i = 0; i < 8; i++) t8[i] = fmaxf(sv[i], sv[i + 8]);
#pragma unroll
      for (int i = 0; i < 4; i++) t8[i] = fmaxf(t8[i], t8[i + 4]);
      float tm = fmaxf(fmaxf(t8[0], t8[1]), fmaxf(t8[2], t8[3]));
      tm = fmaxf(tm, __shfl_xor(tm, 16));
      tm = fmaxf(tm, __shfl_xor(tm, 32));

      if (!__all(tm <= mrun + 8.0f)) {  // defer-max (log2 units)
        const float mn = fmaxf(mrun, tm);
        const float corr = __builtin_amdgcn_exp2f(mrun - mn);
        lsum *= corr;
#pragma unroll
        for (int c = 0; c < 4; c++)
#pragma unroll
          for (int r = 0; r < 4; r++) oa[c][r] *= corr;
        mrun = mn;
      }

#pragma unroll
      for (int i = 0; i < 16; i++)
        sv[i] = __builtin_amdgcn_exp2f(sv[i] - mrun);
      float s8[8];
#pragma unroll
      for (int i = 0; i < 8; i++) s8[i] = sv[i] + sv[i + 8];
#pragma unroll
      for (int i = 0; i < 4; i++) s8[i] = s8[i] + s8[i + 4];
      float rs = (s8[0] + s8[1]) + (s8[2] + s8[3]);
      rs += __shfl_xor(rs, 16);
      rs += __shfl_xor(rs, 32);
      lsum += rs;

#pragma unroll
      for (int mf = 0; mf < 4; mf++) {
        ushort4 w;
        w.x = f2bf(sv[mf * 4 + 0]);
        w.y = f2bf(sv[mf * 4 + 1]);
        w.z = f2bf(sv[mf * 4 + 2]);
        w.w = f2bf(sv[mf * 4 + 3]);
        *(ushort4*)&Ps[wave][lr][mf * 16 + lg * 4] = w;
      }
      asm volatile("" ::: "memory");
      U8 pb[2];
      pb[0].v = *(const bf16x8*)&Ps[wave][lr][lg * 8];
      pb[1].v = *(const bf16x8*)&Ps[wave][lr][32 + lg * 8];
      asm volatile("" ::: "memory");

#pragma unroll
      for (int c = 0; c < 4; c++) {
#pragma unroll
        for (int ks = 0; ks < 2; ks++) {
          U8 vf;
          vf.v = *(const bf16x8*)(Vc + (c * 16 + lr) * 64 + ((ks * 32 + lg * 8) ^ swe));
          oa[c] = __builtin_amdgcn_mfma_f32_16x16x32_bf16(vf.v, pb[ks].v, oa[c], 0, 0, 0);
        }
      }

      block_barrier();
      cur ^= 1;
    }

    const float inv = 1.0f / lsum;
#pragma unroll
    for (int c = 0; c < 4; c++) {
      ushort4 ov;
      ov.x = f2bf(oa[c][0] * inv);
      ov.y = f2bf(oa[c][1] * inv);
      ov.z = f2bf(oa[c][2] * inv);
      ov.w = f2bf(oa[c][3] * inv);
      *(ushort4*)(o + (size_t)(bT + trow) * C + hh * 64 + c * 16 + lg * 4) = ov;
    }
  }
}

// ---------------------------------------------------------------------------
// Orchestration.  Workspace lifetimes (80 MB):
//   0-6 WqkvT (dead after QKV) | 6-8 WpT (dead after proj) | 8-16 W1T (dead
//   after FFN1) | 16-24 W2T (thru FFN2) | 24-32 h (dead after QKV) |
//   32-48 qkb, 48-56 vTb (dead after attn) | 56-64 att -> h2 |
//   24-56 ff1 after FFN1 | x1 = d_out | FFN2 bf16 partials: 0-16 & 64-80.
// ---------------------------------------------------------------------------
extern "C" void kernel_launch(void* const* d_in, const int* in_sizes, int n_in,
                              void* d_out, int out_size, void* d_ws, size_t ws_size,
                              hipStream_t stream) {
  (void)in_sizes; (void)n_in; (void)out_size; (void)ws_size;
  const int T = 2048, C = 1024, M = 2 * T, C4 = 4 * C;

  const float* x     = (const float*)d_in[0];
  const float* Wq    = (const float*)d_in[1];
  const float* Wk    = (const float*)d_in[2];
  const float* Wv    = (const float*)d_in[3];
  const float* Wproj = (const float*)d_in[4];
  const float* bproj = (const float*)d_in[5];
  const float* W1    = (const float*)d_in[6];
  const float* b1    = (const float*)d_in[7];
  const float* W2    = (const float*)d_in[8];
  const float* b2    = (const float*)d_in[9];
  const float* ln1g  = (const float*)d_in[10];
  const float* ln1b  = (const float*)d_in[11];
  const float* ln2g  = (const float*)d_in[12];
  const float* ln2b  = (const float*)d_in[13];
  float* out = (float*)d_out;

  char* ws = (char*)d_ws;
  const size_t MBy = (size_t)1 << 20;
  unsigned short* WqkvT = (unsigned short*)(ws + 0 * MBy);
  unsigned short* WqT = WqkvT;
  unsigned short* WkT = WqkvT + 1024 * 1024;
  unsigned short* WvT = WqkvT + 2048 * 1024;
  unsigned short* WpT = (unsigned short*)(ws + 6 * MBy);
  unsigned short* W1T = (unsigned short*)(ws + 8 * MBy);
  unsigned short* W2T = (unsigned short*)(ws + 16 * MBy);
  unsigned short* h   = (unsigned short*)(ws + 24 * MBy);
  unsigned short* qkb = (unsigned short*)(ws + 32 * MBy);
  unsigned short* vTb = (unsigned short*)(ws + 48 * MBy);
  unsigned short* att = (unsigned short*)(ws + 56 * MBy);
  float* x1 = out;                                    // x1 lives in d_out
  unsigned short* h2  = att;
  unsigned short* ff1 = h;
  unsigned short* ffP01 = (unsigned short*)(ws + 0 * MBy);   // planes 0,1
  unsigned short* ffP23 = (unsigned short*)(ws + 64 * MBy);  // planes 2,3

  const dim3 tb(32, 8);
  transpose_w<<<dim3(2, 32, 16), tb, 0, stream>>>(Wq, WqT, 1024, 64);
  transpose_w<<<dim3(2, 32, 16), tb, 0, stream>>>(Wk, WkT, 1024, 64);
  transpose_w<<<dim3(2, 32, 16), tb, 0, stream>>>(Wv, WvT, 1024, 64);
  transpose_w<<<dim3(32, 32, 1), tb, 0, stream>>>(Wproj, WpT, 1024, 1024);
  transpose_w<<<dim3(128, 32, 1), tb, 0, stream>>>(W1, W1T, 1024, 4096);
  transpose_w<<<dim3(32, 128, 1), tb, 0, stream>>>(W2, W2T, 4096, 1024);

  ln_kernel<<<M, 256, 0, stream>>>(x, ln1g, ln1b, h);

  // Fused QKV (8-phase 256^2): Q cols pre-scaled by 0.125*log2e
  gemm8p<4, 1><<<192, 512, 0, stream>>>(h, WqkvT, qkb, vTb, nullptr, M, 3072, C);

  // attn: XCD-grouped 1-D grid (512 blocks)
  attn_kernel<<<512, 256, 0, stream>>>(qkb, vTb, att);

  // proj (+bproj +x) -> x1 (d_out)
  gemm_lat2<<<512, 256, 0, stream>>>(att, WpT, x1, bproj, x, M, C, C);

  ln_kernel<<<M, 256, 0, stream>>>(x1, ln2g, ln2b, h2);

  // FFN1 (8-phase 256^2): relu(h2 @ W1 + b1) -> bf16
  gemm8p<2, 1><<<256, 512, 0, stream>>>(h2, W1T, ff1, nullptr, b1, M, C4, C);

  // FFN2: split-K=4 8-phase partials (bf16) + fused reduce (+b2 +x1 in-place)
  gemm8p<5, 4><<<256, 512, 0, stream>>>(ff1, W2T, ffP01, ffP23, nullptr, M, C, C4);
  reduce_add4<<<2048, 256, 0, stream>>>(ffP01, ffP23, b2, out, M * C / 4);
}

// Round 11
// 228.764 us; speedup vs baseline: 1.7091x; 1.0407x over previous
//
#include <hip/hip_runtime.h>

// ---------------------------------------------------------------------------
// Types / helpers
// ---------------------------------------------------------------------------
typedef __bf16 bf16x8 __attribute__((ext_vector_type(8)));
typedef float  f32x4  __attribute__((ext_vector_type(4)));

union U8 { bf16x8 v; __bf16 e[8]; unsigned short u[8]; };

// Native HW conversion (v_cvt_*_bf16), RNE.
__device__ __forceinline__ unsigned short f2bf(float f) {
  union { __bf16 b; unsigned short u; } c;
  c.b = (__bf16)f;
  return c.u;
}

__device__ __forceinline__ void async16(const void* g, void* l) {
  __builtin_amdgcn_global_load_lds(
      (__attribute__((address_space(1))) void*)(g),
      (__attribute__((address_space(3))) void*)(l), 16, 0, 0);
}

__device__ __forceinline__ void block_barrier() {
  asm volatile("" ::: "memory");
  __builtin_amdgcn_sched_barrier(0);
  __builtin_amdgcn_s_barrier();
  __builtin_amdgcn_sched_barrier(0);
  asm volatile("" ::: "memory");
}

// ---------------------------------------------------------------------------
// Batched transpose: in fp32 [batch][R][Cc] -> out bf16 [batch*Cc + c][R]
// ---------------------------------------------------------------------------
__global__ __launch_bounds__(256) void transpose_w(
    const float* __restrict__ in, unsigned short* __restrict__ out,
    int R, int Cc) {
  __shared__ float tile[32][33];
  const int batch = blockIdx.z;
  const float* ip = in + (size_t)batch * R * Cc;
  unsigned short* op = out + (size_t)batch * R * Cc;
  const int c0 = blockIdx.x * 32, r0 = blockIdx.y * 32;
  const int tx = threadIdx.x, ty = threadIdx.y;  // 32 x 8
#pragma unroll
  for (int i = 0; i < 32; i += 8)
    tile[ty + i][tx] = ip[(size_t)(r0 + ty + i) * Cc + c0 + tx];
  __syncthreads();
#pragma unroll
  for (int i = 0; i < 32; i += 8)
    op[(size_t)(c0 + ty + i) * R + r0 + tx] = f2bf(tile[tx][ty + i]);
}

// Merged Wq/Wk/Wv transpose: z in [0,48), source picked by z/16.
__global__ __launch_bounds__(256) void transpose_qkv(
    const float* __restrict__ Wq, const float* __restrict__ Wk,
    const float* __restrict__ Wv, unsigned short* __restrict__ out) {
  __shared__ float tile[32][33];
  const int z = blockIdx.z;
  const float* src = (z < 16) ? Wq : (z < 32 ? Wk : Wv);
  const int batch = z & 15;
  const int R = 1024, Cc = 64;
  const float* ip = src + (size_t)batch * R * Cc;
  unsigned short* op = out + (size_t)z * R * Cc;
  const int c0 = blockIdx.x * 32, r0 = blockIdx.y * 32;
  const int tx = threadIdx.x, ty = threadIdx.y;
#pragma unroll
  for (int i = 0; i < 32; i += 8)
    tile[ty + i][tx] = ip[(size_t)(r0 + ty + i) * Cc + c0 + tx];
  __syncthreads();
#pragma unroll
  for (int i = 0; i < 32; i += 8)
    op[(size_t)(c0 + ty + i) * R + r0 + tx] = f2bf(tile[tx][ty + i]);
}

// ---------------------------------------------------------------------------
// LayerNorm over rows of 1024, fp32 in -> bf16 out.
// ---------------------------------------------------------------------------
__global__ __launch_bounds__(256) void ln_kernel(
    const float* __restrict__ x, const float* __restrict__ g,
    const float* __restrict__ bta, unsigned short* __restrict__ out) {
  const int C = 1024;
  const int row = blockIdx.x, tid = threadIdx.x;
  const float4 v = ((const float4*)(x + (size_t)row * C))[tid];
  float s  = v.x + v.y + v.z + v.w;
  float ss = v.x * v.x + v.y * v.y + v.z * v.z + v.w * v.w;
#pragma unroll
  for (int off = 32; off > 0; off >>= 1) {
    s  += __shfl_down(s, off);
    ss += __shfl_down(ss, off);
  }
  __shared__ float r0[4], r1[4];
  const int wave = tid >> 6, lane = tid & 63;
  if (lane == 0) { r0[wave] = s; r1[wave] = ss; }
  __syncthreads();
  s  = r0[0] + r0[1] + r0[2] + r0[3];
  ss = r1[0] + r1[1] + r1[2] + r1[3];
  const float mu   = s * (1.0f / C);
  const float var  = ss * (1.0f / C) - mu * mu;
  const float rstd = rsqrtf(var + 1e-5f);
  const float4 gv = ((const float4*)g)[tid];
  const float4 bv = ((const float4*)bta)[tid];
  ushort4 o;
  o.x = f2bf((v.x - mu) * rstd * gv.x + bv.x);
  o.y = f2bf((v.y - mu) * rstd * gv.y + bv.y);
  o.z = f2bf((v.z - mu) * rstd * gv.z + bv.z);
  o.w = f2bf((v.w - mu) * rstd * gv.w + bv.w);
  ((ushort4*)(out + (size_t)row * C))[tid] = o;
}

// ---------------------------------------------------------------------------
// 128x64-tile latency GEMM (round-6 verified): 512 blocks = 2 blocks/CU.
// C = A*BT^T + bias + resid -> fp32. BK=64, triple-buffered 72 KB LDS,
// 2-tiles-ahead prefetch, counted vmcnt(6), chunk-XOR swizzle (0 conflicts).
// ---------------------------------------------------------------------------
__global__ __launch_bounds__(256, 2) void gemm_lat2(
    const unsigned short* __restrict__ A, const unsigned short* __restrict__ BT,
    float* __restrict__ Cout, const float* __restrict__ bias,
    const float* __restrict__ resid, int M, int N, int K) {
  __shared__ __align__(16) unsigned short As[3][8192];
  __shared__ __align__(16) unsigned short Bs[3][4096];
  const int tid = threadIdx.x;
  const int lane = tid & 63, wave = tid >> 6;
  const int wm = wave >> 1, wn = wave & 1;
  const int lr = lane & 15, lg = lane >> 4;

  const int nwg = gridDim.x;
  const int cpx = nwg >> 3;
  const int swz = ((int)blockIdx.x & 7) * cpx + ((int)blockIdx.x >> 3);
  const int Nt = N >> 6;
  const int g4 = swz / (4 * Nt);
  const int rem = swz - g4 * 4 * Nt;
  const int m0 = (g4 * 4 + (rem & 3)) << 7;
  const int n0 = (rem >> 2) << 6;

  const int srow = tid >> 3;
  const int sc = ((tid & 7) ^ (srow & 7)) << 3;
  const unsigned short* Ag = A + (size_t)(m0 + srow) * K + sc;
  const unsigned short* Bg = BT + (size_t)(n0 + srow) * K + sc;
  const size_t rskip = (size_t)32 * K;

  f32x4 acc[4][2] = {};
  const int nkt = K >> 6;

#define STG(T, B)                                                          \
  {                                                                        \
    const int kt_ = (T) << 6;                                              \
    _Pragma("unroll")                                                      \
    for (int j = 0; j < 4; ++j)                                            \
      async16(Ag + kt_ + (size_t)j * rskip, &As[B][j * 2048 + tid * 8]);   \
    async16(Bg + kt_, &Bs[B][tid * 8]);                                    \
    async16(Bg + kt_ + rskip, &Bs[B][2048 + tid * 8]);                     \
  }

  STG(0, 0);
  STG(1, 1);

  for (int t = 0; t < nkt; ++t) {
    const int buf = t % 3;
    if (t + 1 < nkt) asm volatile("s_waitcnt vmcnt(6)" ::: "memory");
    else             asm volatile("s_waitcnt vmcnt(0)" ::: "memory");
    block_barrier();
    if (t + 2 < nkt) {
      int sb = buf + 2; if (sb >= 3) sb -= 3;
      STG(t + 2, sb);
    }
#pragma unroll
    for (int kh = 0; kh < 2; ++kh) {
      const int kc = ((kh * 4 + lg) ^ (lr & 7)) << 3;
      bf16x8 afr[4], bfr[2];
#pragma unroll
      for (int fm = 0; fm < 4; fm++)
        afr[fm] = *(const bf16x8*)&As[buf][(wm * 64 + fm * 16 + lr) * 64 + kc];
#pragma unroll
      for (int fn = 0; fn < 2; fn++)
        bfr[fn] = *(const bf16x8*)&Bs[buf][(wn * 32 + fn * 16 + lr) * 64 + kc];
#pragma unroll
      for (int fm = 0; fm < 4; fm++)
#pragma unroll
        for (int fn = 0; fn < 2; fn++)
          acc[fm][fn] = __builtin_amdgcn_mfma_f32_16x16x32_bf16(
              afr[fm], bfr[fn], acc[fm][fn], 0, 0, 0);
    }
  }
#undef STG

#pragma unroll
  for (int fn = 0; fn < 2; fn++) {
    const int col = n0 + wn * 32 + fn * 16 + lr;
    const float bv = bias[col];
#pragma unroll
    for (int fm = 0; fm < 4; fm++) {
      const int row0 = m0 + wm * 64 + fm * 16 + lg * 4;
#pragma unroll
      for (int r = 0; r < 4; r++) {
        const size_t idx = (size_t)(row0 + r) * N + col;
        Cout[idx] = acc[fm][fn][r] + bv + resid[idx];
      }
    }
  }
}

// ---------------------------------------------------------------------------
// Split-K reduce (4 planes bf16): out[i] = sum_p P[p][i] + bias + out[i].
// ---------------------------------------------------------------------------
__global__ __launch_bounds__(256) void reduce_add4(
    const unsigned short* __restrict__ p01, const unsigned short* __restrict__ p23,
    const float* __restrict__ bias, float* __restrict__ out, int n4) {
  const int stride = gridDim.x * 256;
#define BF(u) __uint_as_float(((unsigned)(u)) << 16)
  for (int i = blockIdx.x * 256 + threadIdx.x; i < n4; i += stride) {
    const ushort4 a = ((const ushort4*)p01)[i];
    const ushort4 b = ((const ushort4*)p01)[i + n4];
    const ushort4 c = ((const ushort4*)p23)[i];
    const ushort4 d = ((const ushort4*)p23)[i + n4];
    const float4 r = ((const float4*)out)[i];
    const float4 bv = ((const float4*)bias)[i & 255];
    float4 o;
    o.x = (BF(a.x) + BF(b.x)) + (BF(c.x) + BF(d.x)) + r.x + bv.x;
    o.y = (BF(a.y) + BF(b.y)) + (BF(c.y) + BF(d.y)) + r.y + bv.y;
    o.z = (BF(a.z) + BF(b.z)) + (BF(c.z) + BF(d.z)) + r.z + bv.z;
    o.w = (BF(a.w) + BF(b.w)) + (BF(c.w) + BF(d.w)) + r.w + bv.w;
    ((float4*)out)[i] = o;
  }
#undef BF
}

// ---------------------------------------------------------------------------
// 256x256 8-phase deep-pipelined GEMM, optional split-K.
// EPI: 2 = relu(+bias) -> bf16 ; 4 = QKV split (Q cols pre-scaled by
//      0.125*log2e) ; 5 = bf16 partial planes.
// ---------------------------------------------------------------------------
template <int EPI, int SPLITK>
__global__ __launch_bounds__(512, 2) void gemm8p(
    const unsigned short* __restrict__ A, const unsigned short* __restrict__ BT,
    void* __restrict__ Cout, void* __restrict__ Cout2,
    const float* __restrict__ bias, int M, int N, int K) {
  __shared__ __align__(16) unsigned short As[2][2][8192];
  __shared__ __align__(16) unsigned short Bs[2][2][8192];
  const int tid = threadIdx.x;
  const int lane = tid & 63;
  const int wave = tid >> 6;
  const int wm = wave >> 2, wn = wave & 3;  // 2 x 4 wave grid
  const int lr = lane & 15, lg = lane >> 4;

  const int nwg = gridDim.x;
  const int cpx = nwg >> 3;
  const int swz = ((int)blockIdx.x & 7) * cpx + ((int)blockIdx.x >> 3);
  int tile = swz, ks = 0;
  if (SPLITK > 1) {
    const int tilesPer = nwg / SPLITK;
    ks = swz / tilesPer;
    tile = swz - ks * tilesPer;
  }
  const int Ksl = K / SPLITK;
  const int k0 = ks * Ksl;
  const int Nt = N >> 8;
  const int g4 = tile / (4 * Nt);
  const int rem = tile - g4 * 4 * Nt;
  const int m0 = (g4 * 4 + (rem & 3)) << 8;
  const int n0 = (rem >> 2) << 8;

  const int srow = tid >> 2;
  const int scg = ((tid & 3) ^ ((srow >> 1) & 3)) << 3;
  const unsigned short* Ag = A + (size_t)(m0 + srow) * K + k0 + scg;
  const unsigned short* Bg = BT + (size_t)(n0 + srow) * K + k0 + scg;
  const size_t rskip = (size_t)128 * K;
  const int l8 = tid * 8;

  const int kch = (lg ^ ((lr >> 1) & 3)) << 3;

  f32x4 acc[8][4] = {};
  bf16x8 afr[4], bfr[4];
  const int nkt = Ksl >> 6;

  async16(Ag, &As[0][0][l8]);            async16(Ag + rskip, &As[0][0][l8 + 4096]);
  async16(Bg, &Bs[0][0][l8]);            async16(Bg + rskip, &Bs[0][0][l8 + 4096]);
  async16(Ag + 32, &As[0][1][l8]);       async16(Ag + 32 + rskip, &As[0][1][l8 + 4096]);
  async16(Bg + 32, &Bs[0][1][l8]);       async16(Bg + 32 + rskip, &Bs[0][1][l8 + 4096]);
  async16(Ag + 64, &As[1][0][l8]);       async16(Ag + 64 + rskip, &As[1][0][l8 + 4096]);
  async16(Bg + 64, &Bs[1][0][l8]);       async16(Bg + 64 + rskip, &Bs[1][0][l8 + 4096]);
  asm volatile("s_waitcnt vmcnt(4)" ::: "memory");
  block_barrier();

  for (int t = 0; t < nkt; ++t) {
    const int buf = t & 1, nbuf = buf ^ 1;
    const int kt1 = (t + 1) << 6, kt2 = (t + 2) << 6;
    const bool s1 = (t + 1 < nkt), s2 = (t + 2 < nkt);

    // ---- phase 1: ks=0, mh=0 ----
#pragma unroll
    for (int fm = 0; fm < 4; fm++)
      afr[fm] = *(const bf16x8*)&As[buf][0][(wm * 128 + fm * 16 + lr) * 32 + kch];
#pragma unroll
    for (int fn = 0; fn < 4; fn++)
      bfr[fn] = *(const bf16x8*)&Bs[buf][0][(wn * 64 + fn * 16 + lr) * 32 + kch];
    if (s1) {
      async16(Ag + kt1 + 32, &As[nbuf][1][l8]);
      async16(Ag + kt1 + 32 + rskip, &As[nbuf][1][l8 + 4096]);
    }
    block_barrier();
    __builtin_amdgcn_s_setprio(1);
#pragma unroll
    for (int fm = 0; fm < 4; fm++)
#pragma unroll
      for (int fn = 0; fn < 4; fn++)
        acc[fm][fn] = __builtin_amdgcn_mfma_f32_16x16x32_bf16(afr[fm], bfr[fn], acc[fm][fn], 0, 0, 0);
    __builtin_amdgcn_s_setprio(0);
    block_barrier();

    // ---- phase 2: ks=0, mh=1 ----
#pragma unroll
    for (int fm = 0; fm < 4; fm++)
      afr[fm] = *(const bf16x8*)&As[buf][0][(wm * 128 + 64 + fm * 16 + lr) * 32 + kch];
    if (s1) {
      async16(Bg + kt1 + 32, &Bs[nbuf][1][l8]);
      async16(Bg + kt1 + 32 + rskip, &Bs[nbuf][1][l8 + 4096]);
    }
    block_barrier();
    __builtin_amdgcn_s_setprio(1);
#pragma unroll
    for (int fm = 0; fm < 4; fm++)
#pragma unroll
      for (int fn = 0; fn < 4; fn++)
        acc[4 + fm][fn] = __builtin_amdgcn_mfma_f32_16x16x32_bf16(afr[fm], bfr[fn], acc[4 + fm][fn], 0, 0, 0);
    __builtin_amdgcn_s_setprio(0);
    block_barrier();

    // ---- phase 3: ks=1, mh=0 ----
#pragma unroll
    for (int fm = 0; fm < 4; fm++)
      afr[fm] = *(const bf16x8*)&As[buf][1][(wm * 128 + fm * 16 + lr) * 32 + kch];
#pragma unroll
    for (int fn = 0; fn < 4; fn++)
      bfr[fn] = *(const bf16x8*)&Bs[buf][1][(wn * 64 + fn * 16 + lr) * 32 + kch];
    if (s2) {
      async16(Ag + kt2, &As[buf][0][l8]);
      async16(Ag + kt2 + rskip, &As[buf][0][l8 + 4096]);
    }
    block_barrier();
    __builtin_amdgcn_s_setprio(1);
#pragma unroll
    for (int fm = 0; fm < 4; fm++)
#pragma unroll
      for (int fn = 0; fn < 4; fn++)
        acc[fm][fn] = __builtin_amdgcn_mfma_f32_16x16x32_bf16(afr[fm], bfr[fn], acc[fm][fn], 0, 0, 0);
    __builtin_amdgcn_s_setprio(0);
    block_barrier();

    // ---- phase 4: ks=1, mh=1 ----
#pragma unroll
    for (int fm = 0; fm < 4; fm++)
      afr[fm] = *(const bf16x8*)&As[buf][1][(wm * 128 + 64 + fm * 16 + lr) * 32 + kch];
    if (s2) {
      async16(Bg + kt2, &Bs[buf][0][l8]);
      async16(Bg + kt2 + rskip, &Bs[buf][0][l8 + 4096]);
    }
    block_barrier();
    __builtin_amdgcn_s_setprio(1);
#pragma unroll
    for (int fm = 0; fm < 4; fm++)
#pragma unroll
      for (int fn = 0; fn < 4; fn++)
        acc[4 + fm][fn] = __builtin_amdgcn_mfma_f32_16x16x32_bf16(afr[fm], bfr[fn], acc[4 + fm][fn], 0, 0, 0);
    __builtin_amdgcn_s_setprio(0);
    if (s2) asm volatile("s_waitcnt vmcnt(4)" ::: "memory");
    else    asm volatile("s_waitcnt vmcnt(0)" ::: "memory");
    block_barrier();
  }

#pragma unroll
  for (int fn = 0; fn < 4; fn++) {
    const int col = n0 + wn * 64 + fn * 16 + lr;
    float bv = 0.0f;
    if (EPI == 2) bv = bias[col];
#pragma unroll
    for (int fm = 0; fm < 8; fm++) {
      const int row0 = m0 + wm * 128 + fm * 16 + lg * 4;
      if (EPI == 2) {
#pragma unroll
        for (int r = 0; r < 4; r++)
          ((unsigned short*)Cout)[(size_t)(row0 + r) * N + col] =
              f2bf(fmaxf(acc[fm][fn][r] + bv, 0.0f));
      } else if (EPI == 5) {
        unsigned short* P = (unsigned short*)(ks < 2 ? Cout : Cout2) +
                            (size_t)(ks & 1) * M * N;
#pragma unroll
        for (int r = 0; r < 4; r++)
          P[(size_t)(row0 + r) * N + col] = f2bf(acc[fm][fn][r]);
      } else {  // EPI 4: QKV split; Q cols scaled into exp2 domain
        if (col < 2048) {
#pragma unroll
          for (int r = 0; r < 4; r++) {
            float val = acc[fm][fn][r];
            if (col < 1024) val *= 0.18033688011112042f;  // 0.125 * log2(e)
            ((unsigned short*)Cout)[(size_t)(row0 + r) * 2048 + col] = f2bf(val);
          }
        } else {
          ushort4 ov;
          ov.x = f2bf(acc[fm][fn][0]);
          ov.y = f2bf(acc[fm][fn][1]);
          ov.z = f2bf(acc[fm][fn][2]);
          ov.w = f2bf(acc[fm][fn][3]);
          *(ushort4*)((unsigned short*)Cout2 + (size_t)(col - 2048) * 4096 + row0) = ov;
        }
      }
    }
  }
}

// ---------------------------------------------------------------------------
// Flash attention (causal), swapped-operand, LDS-staged K/V, double-buffered,
// exp2-domain softmax. 1024 blocks, one q-tile each; XCD-grouped + LPT:
//   id = (bh&7) + 8*(bhHi + 4*(31-qt))   =>  id%8 == bh&7 (L2 locality)
//   and qt descends with dispatch order (longest-first packing).
// 41 KB LDS -> 3 blocks/CU co-resident (3 waves/SIMD TLP on the chain).
// ---------------------------------------------------------------------------
__global__ __launch_bounds__(256, 3) void attn_kernel(
    const unsigned short* __restrict__ qk, const unsigned short* __restrict__ vT,
    unsigned short* __restrict__ o) {
  const int T = 2048, C = 1024, QKS = 2048;
  const int tid = threadIdx.x;
  const int wave = tid >> 6, lane = tid & 63;
  const int lr = lane & 15, lg = lane >> 4;

  // decode XCD-grouped LPT mapping
  const int id = (int)blockIdx.x;
  const int rest = id >> 3;           // [0,128)
  const int bhHi = rest & 3;
  const int qt = 31 - (rest >> 2);    // longest first
  const int bh = (bhHi << 3) | (id & 7);
  const int b = bh >> 4, hh = bh & 15;

  const size_t rowb = (size_t)b * T * QKS;
  const int qcol = hh * 64;
  const int kcol = 1024 + hh * 64;
  const int vrow0 = hh * 64;
  const size_t bT = (size_t)b * T;
  const int swe = (lr & 7) << 3;

  __shared__ __align__(16) unsigned short Ks[2][64 * 64];
  __shared__ __align__(16) unsigned short Vs[2][64 * 64];
  __shared__ __align__(16) unsigned short Ps[4][16][72];

  const int rw = tid >> 3;
  const int c8 = ((tid & 7) ^ (rw & 7)) << 3;

  const int qbase = qt * 64 + wave * 16;
  const int trow = qbase + lr;

  U8 qf[2];
#pragma unroll
  for (int j = 0; j < 2; j++)
    qf[j].v = *(const bf16x8*)(qk + rowb + (size_t)trow * QKS + qcol + j * 32 + lg * 8);
  asm volatile("s_waitcnt vmcnt(0)" ::: "memory");

  async16(qk + rowb + (size_t)rw * QKS + kcol + c8, Ks[0] + tid * 8);
  async16(qk + rowb + (size_t)(32 + rw) * QKS + kcol + c8, Ks[0] + 2048 + tid * 8);
  async16(vT + (size_t)(vrow0 + rw) * 4096 + bT + c8, Vs[0] + tid * 8);
  async16(vT + (size_t)(vrow0 + 32 + rw) * 4096 + bT + c8, Vs[0] + 2048 + tid * 8);

  f32x4 oa[4] = {};
  float mrun = -1e30f, lsum = 0.0f;
  int cur = 0;

  for (int sb = 0; sb <= qt; ++sb) {
    if (sb < qt) {
      const int s1 = (sb + 1) * 64;
      const int nb = cur ^ 1;
      async16(qk + rowb + (size_t)(s1 + rw) * QKS + kcol + c8, Ks[nb] + tid * 8);
      async16(qk + rowb + (size_t)(s1 + 32 + rw) * QKS + kcol + c8, Ks[nb] + 2048 + tid * 8);
      async16(vT + (size_t)(vrow0 + rw) * 4096 + bT + s1 + c8, Vs[nb] + tid * 8);
      async16(vT + (size_t)(vrow0 + 32 + rw) * 4096 + bT + s1 + c8, Vs[nb] + 2048 + tid * 8);
      asm volatile("s_waitcnt vmcnt(4)" ::: "memory");
    } else {
      asm volatile("s_waitcnt vmcnt(0)" ::: "memory");
    }
    block_barrier();

    const unsigned short* Kc = Ks[cur];
    const unsigned short* Vc = Vs[cur];
    const int s0 = sb * 64;

    f32x4 sa[4] = {};
    __builtin_amdgcn_s_setprio(1);
#pragma unroll
    for (int j = 0; j < 2; j++) {
#pragma unroll
      for (int mf = 0; mf < 4; mf++) {
        U8 kf;
        kf.v = *(const bf16x8*)(Kc + (mf * 16 + lr) * 64 + ((j * 32 + lg * 8) ^ swe));
        sa[mf] = __builtin_amdgcn_mfma_f32_16x16x32_bf16(kf.v, qf[j].v, sa[mf], 0, 0, 0);
      }
    }
    __builtin_amdgcn_s_setprio(0);
    float sv[16];
#pragma unroll
    for (int mf = 0; mf < 4; mf++)
#pragma unroll
      for (int r = 0; r < 4; r++) sv[mf * 4 + r] = sa[mf][r];  // log2-scaled

    if (sb == qt) {
#pragma unroll
      for (int mf = 0; mf < 4; mf++)
#pragma unroll
        for (int r = 0; r < 4; r++)
          if (s0 + mf * 16 + lg * 4 + r > trow) sv[mf * 4 + r] = -1e30f;
    }

    float t8[8];
#pragma unroll
    for (int i = 0; i < 8; i++) t8[i] = fmaxf(sv[i], sv[i + 8]);
#pragma unroll
    for (int i = 0; i < 4; i++) t8[i] = fmaxf(t8[i], t8[i + 4]);
    float tm = fmaxf(fmaxf(t8[0], t8[1]), fmaxf(t8[2], t8[3]));
    tm = fmaxf(tm, __shfl_xor(tm, 16));
    tm = fmaxf(tm, __shfl_xor(tm, 32));

    if (!__all(tm <= mrun + 8.0f)) {  // defer-max (log2 units)
      const float mn = fmaxf(mrun, tm);
      const float corr = __builtin_amdgcn_exp2f(mrun - mn);
      lsum *= corr;
#pragma unroll
      for (int c = 0; c < 4; c++)
#pragma unroll
        for (int r = 0; r < 4; r++) oa[c][r] *= corr;
      mrun = mn;
    }

#pragma unroll
    for (int i = 0; i < 16; i++)
      sv[i] = __builtin_amdgcn_exp2f(sv[i] - mrun);
    float s8[8];
#pragma unroll
    for (int i = 0; i < 8; i++) s8[i] = sv[i] + sv[i + 8];
#pragma unroll
    for (int i = 0; i < 4; i++) s8[i] = s8[i] + s8[i + 4];
    float rs = (s8[0] + s8[1]) + (s8[2] + s8[3]);
    rs += __shfl_xor(rs, 16);
    rs += __shfl_xor(rs, 32);
    lsum += rs;

#pragma unroll
    for (int mf = 0; mf < 4; mf++) {
      ushort4 w;
      w.x = f2bf(sv[mf * 4 + 0]);
      w.y = f2bf(sv[mf * 4 + 1]);
      w.z = f2bf(sv[mf * 4 + 2]);
      w.w = f2bf(sv[mf * 4 + 3]);
      *(ushort4*)&Ps[wave][lr][mf * 16 + lg * 4] = w;
    }
    asm volatile("" ::: "memory");
    U8 pb[2];
    pb[0].v = *(const bf16x8*)&Ps[wave][lr][lg * 8];
    pb[1].v = *(const bf16x8*)&Ps[wave][lr][32 + lg * 8];
    asm volatile("" ::: "memory");

    __builtin_amdgcn_s_setprio(1);
#pragma unroll
    for (int c = 0; c < 4; c++) {
#pragma unroll
      for (int ks = 0; ks < 2; ks++) {
        U8 vf;
        vf.v = *(const bf16x8*)(Vc + (c * 16 + lr) * 64 + ((ks * 32 + lg * 8) ^ swe));
        oa[c] = __builtin_amdgcn_mfma_f32_16x16x32_bf16(vf.v, pb[ks].v, oa[c], 0, 0, 0);
      }
    }
    __builtin_amdgcn_s_setprio(0);

    block_barrier();
    cur ^= 1;
  }

  const float inv = 1.0f / lsum;
#pragma unroll
  for (int c = 0; c < 4; c++) {
    ushort4 ov;
    ov.x = f2bf(oa[c][0] * inv);
    ov.y = f2bf(oa[c][1] * inv);
    ov.z = f2bf(oa[c][2] * inv);
    ov.w = f2bf(oa[c][3] * inv);
    *(ushort4*)(o + (size_t)(bT + trow) * C + hh * 64 + c * 16 + lg * 4) = ov;
  }
}

// ---------------------------------------------------------------------------
// Orchestration.  Workspace lifetimes (80 MB):
//   0-6 WqkvT (dead after QKV) | 6-8 WpT (dead after proj) | 8-16 W1T (dead
//   after FFN1) | 16-24 W2T (thru FFN2) | 24-32 h (dead after QKV) |
//   32-48 qkb, 48-56 vTb (dead after attn) | 56-64 att -> h2 |
//   24-56 ff1 after FFN1 | x1 = d_out | FFN2 bf16 partials: 0-16 & 64-80.
// ---------------------------------------------------------------------------
extern "C" void kernel_launch(void* const* d_in, const int* in_sizes, int n_in,
                              void* d_out, int out_size, void* d_ws, size_t ws_size,
                              hipStream_t stream) {
  (void)in_sizes; (void)n_in; (void)out_size; (void)ws_size;
  const int T = 2048, C = 1024, M = 2 * T, C4 = 4 * C;

  const float* x     = (const float*)d_in[0];
  const float* Wq    = (const float*)d_in[1];
  const float* Wk    = (const float*)d_in[2];
  const float* Wv    = (const float*)d_in[3];
  const float* Wproj = (const float*)d_in[4];
  const float* bproj = (const float*)d_in[5];
  const float* W1    = (const float*)d_in[6];
  const float* b1    = (const float*)d_in[7];
  const float* W2    = (const float*)d_in[8];
  const float* b2    = (const float*)d_in[9];
  const float* ln1g  = (const float*)d_in[10];
  const float* ln1b  = (const float*)d_in[11];
  const float* ln2g  = (const float*)d_in[12];
  const float* ln2b  = (const float*)d_in[13];
  float* out = (float*)d_out;

  char* ws = (char*)d_ws;
  const size_t MBy = (size_t)1 << 20;
  unsigned short* WqkvT = (unsigned short*)(ws + 0 * MBy);
  unsigned short* WpT = (unsigned short*)(ws + 6 * MBy);
  unsigned short* W1T = (unsigned short*)(ws + 8 * MBy);
  unsigned short* W2T = (unsigned short*)(ws + 16 * MBy);
  unsigned short* h   = (unsigned short*)(ws + 24 * MBy);
  unsigned short* qkb = (unsigned short*)(ws + 32 * MBy);
  unsigned short* vTb = (unsigned short*)(ws + 48 * MBy);
  unsigned short* att = (unsigned short*)(ws + 56 * MBy);
  float* x1 = out;                                    // x1 lives in d_out
  unsigned short* h2  = att;
  unsigned short* ff1 = h;
  unsigned short* ffP01 = (unsigned short*)(ws + 0 * MBy);   // planes 0,1
  unsigned short* ffP23 = (unsigned short*)(ws + 64 * MBy);  // planes 2,3

  const dim3 tb(32, 8);
  transpose_qkv<<<dim3(2, 32, 48), tb, 0, stream>>>(Wq, Wk, Wv, WqkvT);
  transpose_w<<<dim3(32, 32, 1), tb, 0, stream>>>(Wproj, WpT, 1024, 1024);
  transpose_w<<<dim3(128, 32, 1), tb, 0, stream>>>(W1, W1T, 1024, 4096);
  transpose_w<<<dim3(32, 128, 1), tb, 0, stream>>>(W2, W2T, 4096, 1024);

  ln_kernel<<<M, 256, 0, stream>>>(x, ln1g, ln1b, h);

  // Fused QKV (8-phase 256^2): Q cols pre-scaled by 0.125*log2e
  gemm8p<4, 1><<<192, 512, 0, stream>>>(h, WqkvT, qkb, vTb, nullptr, M, 3072, C);

  // attn: 1024 blocks, XCD-grouped + LPT, 3 blocks/CU
  attn_kernel<<<1024, 256, 0, stream>>>(qkb, vTb, att);

  // proj (+bproj +x) -> x1 (d_out)
  gemm_lat2<<<512, 256, 0, stream>>>(att, WpT, x1, bproj, x, M, C, C);

  ln_kernel<<<M, 256, 0, stream>>>(x1, ln2g, ln2b, h2);

  // FFN1 (8-phase 256^2): relu(h2 @ W1 + b1) -> bf16
  gemm8p<2, 1><<<256, 512, 0, stream>>>(h2, W1T, ff1, nullptr, b1, M, C4, C);

  // FFN2: split-K=4 8-phase partials (bf16) + fused reduce (+b2 +x1 in-place)
  gemm8p<5, 4><<<256, 512, 0, stream>>>(ff1, W2T, ffP01, ffP23, nullptr, M, C, C4);
  reduce_add4<<<2048, 256, 0, stream>>>(ffP01, ffP23, b2, out, M * C / 4);
}

// Round 12
// 219.574 us; speedup vs baseline: 1.7806x; 1.0418x over previous
//
#include <hip/hip_runtime.h>

// ---------------------------------------------------------------------------
// Types / helpers
// ---------------------------------------------------------------------------
typedef __bf16 bf16x8 __attribute__((ext_vector_type(8)));
typedef float  f32x4  __attribute__((ext_vector_type(4)));

union U8 { bf16x8 v; __bf16 e[8]; unsigned short u[8]; };

// Native HW conversion (v_cvt_*_bf16), RNE.
__device__ __forceinline__ unsigned short f2bf(float f) {
  union { __bf16 b; unsigned short u; } c;
  c.b = (__bf16)f;
  return c.u;
}

__device__ __forceinline__ void async16(const void* g, void* l) {
  __builtin_amdgcn_global_load_lds(
      (__attribute__((address_space(1))) void*)(g),
      (__attribute__((address_space(3))) void*)(l), 16, 0, 0);
}

__device__ __forceinline__ void block_barrier() {
  asm volatile("" ::: "memory");
  __builtin_amdgcn_sched_barrier(0);
  __builtin_amdgcn_s_barrier();
  __builtin_amdgcn_sched_barrier(0);
  asm volatile("" ::: "memory");
}

// ---------------------------------------------------------------------------
// Batched transpose: in fp32 [batch][R][Cc] -> out bf16 [batch*Cc + c][R]
// ---------------------------------------------------------------------------
__global__ __launch_bounds__(256) void transpose_w(
    const float* __restrict__ in, unsigned short* __restrict__ out,
    int R, int Cc) {
  __shared__ float tile[32][33];
  const int batch = blockIdx.z;
  const float* ip = in + (size_t)batch * R * Cc;
  unsigned short* op = out + (size_t)batch * R * Cc;
  const int c0 = blockIdx.x * 32, r0 = blockIdx.y * 32;
  const int tx = threadIdx.x, ty = threadIdx.y;  // 32 x 8
#pragma unroll
  for (int i = 0; i < 32; i += 8)
    tile[ty + i][tx] = ip[(size_t)(r0 + ty + i) * Cc + c0 + tx];
  __syncthreads();
#pragma unroll
  for (int i = 0; i < 32; i += 8)
    op[(size_t)(c0 + ty + i) * R + r0 + tx] = f2bf(tile[tx][ty + i]);
}

// Merged Wq/Wk/Wv transpose: z in [0,48), source picked by z/16.
__global__ __launch_bounds__(256) void transpose_qkv(
    const float* __restrict__ Wq, const float* __restrict__ Wk,
    const float* __restrict__ Wv, unsigned short* __restrict__ out) {
  __shared__ float tile[32][33];
  const int z = blockIdx.z;
  const float* src = (z < 16) ? Wq : (z < 32 ? Wk : Wv);
  const int batch = z & 15;
  const int R = 1024, Cc = 64;
  const float* ip = src + (size_t)batch * R * Cc;
  unsigned short* op = out + (size_t)z * R * Cc;
  const int c0 = blockIdx.x * 32, r0 = blockIdx.y * 32;
  const int tx = threadIdx.x, ty = threadIdx.y;
#pragma unroll
  for (int i = 0; i < 32; i += 8)
    tile[ty + i][tx] = ip[(size_t)(r0 + ty + i) * Cc + c0 + tx];
  __syncthreads();
#pragma unroll
  for (int i = 0; i < 32; i += 8)
    op[(size_t)(c0 + ty + i) * R + r0 + tx] = f2bf(tile[tx][ty + i]);
}

// ---------------------------------------------------------------------------
// LayerNorm over rows of 1024, fp32 in -> bf16 out.
// ---------------------------------------------------------------------------
__global__ __launch_bounds__(256) void ln_kernel(
    const float* __restrict__ x, const float* __restrict__ g,
    const float* __restrict__ bta, unsigned short* __restrict__ out) {
  const int C = 1024;
  const int row = blockIdx.x, tid = threadIdx.x;
  const float4 v = ((const float4*)(x + (size_t)row * C))[tid];
  float s  = v.x + v.y + v.z + v.w;
  float ss = v.x * v.x + v.y * v.y + v.z * v.z + v.w * v.w;
#pragma unroll
  for (int off = 32; off > 0; off >>= 1) {
    s  += __shfl_down(s, off);
    ss += __shfl_down(ss, off);
  }
  __shared__ float r0[4], r1[4];
  const int wave = tid >> 6, lane = tid & 63;
  if (lane == 0) { r0[wave] = s; r1[wave] = ss; }
  __syncthreads();
  s  = r0[0] + r0[1] + r0[2] + r0[3];
  ss = r1[0] + r1[1] + r1[2] + r1[3];
  const float mu   = s * (1.0f / C);
  const float var  = ss * (1.0f / C) - mu * mu;
  const float rstd = rsqrtf(var + 1e-5f);
  const float4 gv = ((const float4*)g)[tid];
  const float4 bv = ((const float4*)bta)[tid];
  ushort4 o;
  o.x = f2bf((v.x - mu) * rstd * gv.x + bv.x);
  o.y = f2bf((v.y - mu) * rstd * gv.y + bv.y);
  o.z = f2bf((v.z - mu) * rstd * gv.z + bv.z);
  o.w = f2bf((v.w - mu) * rstd * gv.w + bv.w);
  ((ushort4*)(out + (size_t)row * C))[tid] = o;
}

// ---------------------------------------------------------------------------
// 128x64-tile latency GEMM (round-6 verified): 512 blocks = 2 blocks/CU.
// C = A*BT^T + bias + resid -> fp32. BK=64, triple-buffered 72 KB LDS,
// 2-tiles-ahead prefetch, counted vmcnt(6), chunk-XOR swizzle (0 conflicts).
// ---------------------------------------------------------------------------
__global__ __launch_bounds__(256, 2) void gemm_lat2(
    const unsigned short* __restrict__ A, const unsigned short* __restrict__ BT,
    float* __restrict__ Cout, const float* __restrict__ bias,
    const float* __restrict__ resid, int M, int N, int K) {
  __shared__ __align__(16) unsigned short As[3][8192];
  __shared__ __align__(16) unsigned short Bs[3][4096];
  const int tid = threadIdx.x;
  const int lane = tid & 63, wave = tid >> 6;
  const int wm = wave >> 1, wn = wave & 1;
  const int lr = lane & 15, lg = lane >> 4;

  const int nwg = gridDim.x;
  const int cpx = nwg >> 3;
  const int swz = ((int)blockIdx.x & 7) * cpx + ((int)blockIdx.x >> 3);
  const int Nt = N >> 6;
  const int g4 = swz / (4 * Nt);
  const int rem = swz - g4 * 4 * Nt;
  const int m0 = (g4 * 4 + (rem & 3)) << 7;
  const int n0 = (rem >> 2) << 6;

  const int srow = tid >> 3;
  const int sc = ((tid & 7) ^ (srow & 7)) << 3;
  const unsigned short* Ag = A + (size_t)(m0 + srow) * K + sc;
  const unsigned short* Bg = BT + (size_t)(n0 + srow) * K + sc;
  const size_t rskip = (size_t)32 * K;

  f32x4 acc[4][2] = {};
  const int nkt = K >> 6;

#define STG(T, B)                                                          \
  {                                                                        \
    const int kt_ = (T) << 6;                                              \
    _Pragma("unroll")                                                      \
    for (int j = 0; j < 4; ++j)                                            \
      async16(Ag + kt_ + (size_t)j * rskip, &As[B][j * 2048 + tid * 8]);   \
    async16(Bg + kt_, &Bs[B][tid * 8]);                                    \
    async16(Bg + kt_ + rskip, &Bs[B][2048 + tid * 8]);                     \
  }

  STG(0, 0);
  STG(1, 1);

  for (int t = 0; t < nkt; ++t) {
    const int buf = t % 3;
    if (t + 1 < nkt) asm volatile("s_waitcnt vmcnt(6)" ::: "memory");
    else             asm volatile("s_waitcnt vmcnt(0)" ::: "memory");
    block_barrier();
    if (t + 2 < nkt) {
      int sb = buf + 2; if (sb >= 3) sb -= 3;
      STG(t + 2, sb);
    }
#pragma unroll
    for (int kh = 0; kh < 2; ++kh) {
      const int kc = ((kh * 4 + lg) ^ (lr & 7)) << 3;
      bf16x8 afr[4], bfr[2];
#pragma unroll
      for (int fm = 0; fm < 4; fm++)
        afr[fm] = *(const bf16x8*)&As[buf][(wm * 64 + fm * 16 + lr) * 64 + kc];
#pragma unroll
      for (int fn = 0; fn < 2; fn++)
        bfr[fn] = *(const bf16x8*)&Bs[buf][(wn * 32 + fn * 16 + lr) * 64 + kc];
#pragma unroll
      for (int fm = 0; fm < 4; fm++)
#pragma unroll
        for (int fn = 0; fn < 2; fn++)
          acc[fm][fn] = __builtin_amdgcn_mfma_f32_16x16x32_bf16(
              afr[fm], bfr[fn], acc[fm][fn], 0, 0, 0);
    }
  }
#undef STG

#pragma unroll
  for (int fn = 0; fn < 2; fn++) {
    const int col = n0 + wn * 32 + fn * 16 + lr;
    const float bv = bias[col];
#pragma unroll
    for (int fm = 0; fm < 4; fm++) {
      const int row0 = m0 + wm * 64 + fm * 16 + lg * 4;
#pragma unroll
      for (int r = 0; r < 4; r++) {
        const size_t idx = (size_t)(row0 + r) * N + col;
        Cout[idx] = acc[fm][fn][r] + bv + resid[idx];
      }
    }
  }
}

// ---------------------------------------------------------------------------
// Split-K reduce (4 planes bf16): out[i] = sum_p P[p][i] + bias + out[i].
// ---------------------------------------------------------------------------
__global__ __launch_bounds__(256) void reduce_add4(
    const unsigned short* __restrict__ p01, const unsigned short* __restrict__ p23,
    const float* __restrict__ bias, float* __restrict__ out, int n4) {
  const int stride = gridDim.x * 256;
#define BF(u) __uint_as_float(((unsigned)(u)) << 16)
  for (int i = blockIdx.x * 256 + threadIdx.x; i < n4; i += stride) {
    const ushort4 a = ((const ushort4*)p01)[i];
    const ushort4 b = ((const ushort4*)p01)[i + n4];
    const ushort4 c = ((const ushort4*)p23)[i];
    const ushort4 d = ((const ushort4*)p23)[i + n4];
    const float4 r = ((const float4*)out)[i];
    const float4 bv = ((const float4*)bias)[i & 255];
    float4 o;
    o.x = (BF(a.x) + BF(b.x)) + (BF(c.x) + BF(d.x)) + r.x + bv.x;
    o.y = (BF(a.y) + BF(b.y)) + (BF(c.y) + BF(d.y)) + r.y + bv.y;
    o.z = (BF(a.z) + BF(b.z)) + (BF(c.z) + BF(d.z)) + r.z + bv.z;
    o.w = (BF(a.w) + BF(b.w)) + (BF(c.w) + BF(d.w)) + r.w + bv.w;
    ((float4*)out)[i] = o;
  }
#undef BF
}

// ---------------------------------------------------------------------------
// 256x256 8-phase deep-pipelined GEMM, optional split-K, with COALESCED
// LDS-roundtrip epilogue (writes were 128x2B scalar stores -> now 16x16B).
// EPI: 2 = relu(+bias) -> bf16 ; 4 = QKV split (Q cols pre-scaled by
//      0.125*log2e) ; 5 = bf16 partial planes.
// ---------------------------------------------------------------------------
template <int EPI, int SPLITK>
__global__ __launch_bounds__(512, 2) void gemm8p(
    const unsigned short* __restrict__ A, const unsigned short* __restrict__ BT,
    void* __restrict__ Cout, void* __restrict__ Cout2,
    const float* __restrict__ bias, int M, int N, int K) {
  __shared__ __align__(16) unsigned short As[2][2][8192];
  __shared__ __align__(16) unsigned short Bs[2][2][8192];
  const int tid = threadIdx.x;
  const int lane = tid & 63;
  const int wave = tid >> 6;
  const int wm = wave >> 2, wn = wave & 3;  // 2 x 4 wave grid
  const int lr = lane & 15, lg = lane >> 4;

  const int nwg = gridDim.x;
  const int cpx = nwg >> 3;
  const int swz = ((int)blockIdx.x & 7) * cpx + ((int)blockIdx.x >> 3);
  int tile = swz, ks = 0;
  if (SPLITK > 1) {
    const int tilesPer = nwg / SPLITK;
    ks = swz / tilesPer;
    tile = swz - ks * tilesPer;
  }
  const int Ksl = K / SPLITK;
  const int k0 = ks * Ksl;
  const int Nt = N >> 8;
  const int g4 = tile / (4 * Nt);
  const int rem = tile - g4 * 4 * Nt;
  const int m0 = (g4 * 4 + (rem & 3)) << 8;
  const int n0 = (rem >> 2) << 8;

  const int srow = tid >> 2;
  const int scg = ((tid & 3) ^ ((srow >> 1) & 3)) << 3;
  const unsigned short* Ag = A + (size_t)(m0 + srow) * K + k0 + scg;
  const unsigned short* Bg = BT + (size_t)(n0 + srow) * K + k0 + scg;
  const size_t rskip = (size_t)128 * K;
  const int l8 = tid * 8;

  const int kch = (lg ^ ((lr >> 1) & 3)) << 3;

  f32x4 acc[8][4] = {};
  bf16x8 afr[4], bfr[4];
  const int nkt = Ksl >> 6;

  async16(Ag, &As[0][0][l8]);            async16(Ag + rskip, &As[0][0][l8 + 4096]);
  async16(Bg, &Bs[0][0][l8]);            async16(Bg + rskip, &Bs[0][0][l8 + 4096]);
  async16(Ag + 32, &As[0][1][l8]);       async16(Ag + 32 + rskip, &As[0][1][l8 + 4096]);
  async16(Bg + 32, &Bs[0][1][l8]);       async16(Bg + 32 + rskip, &Bs[0][1][l8 + 4096]);
  async16(Ag + 64, &As[1][0][l8]);       async16(Ag + 64 + rskip, &As[1][0][l8 + 4096]);
  async16(Bg + 64, &Bs[1][0][l8]);       async16(Bg + 64 + rskip, &Bs[1][0][l8 + 4096]);
  asm volatile("s_waitcnt vmcnt(4)" ::: "memory");
  block_barrier();

  for (int t = 0; t < nkt; ++t) {
    const int buf = t & 1, nbuf = buf ^ 1;
    const int kt1 = (t + 1) << 6, kt2 = (t + 2) << 6;
    const bool s1 = (t + 1 < nkt), s2 = (t + 2 < nkt);

    // ---- phase 1: ks=0, mh=0 ----
#pragma unroll
    for (int fm = 0; fm < 4; fm++)
      afr[fm] = *(const bf16x8*)&As[buf][0][(wm * 128 + fm * 16 + lr) * 32 + kch];
#pragma unroll
    for (int fn = 0; fn < 4; fn++)
      bfr[fn] = *(const bf16x8*)&Bs[buf][0][(wn * 64 + fn * 16 + lr) * 32 + kch];
    if (s1) {
      async16(Ag + kt1 + 32, &As[nbuf][1][l8]);
      async16(Ag + kt1 + 32 + rskip, &As[nbuf][1][l8 + 4096]);
    }
    block_barrier();
    __builtin_amdgcn_s_setprio(1);
#pragma unroll
    for (int fm = 0; fm < 4; fm++)
#pragma unroll
      for (int fn = 0; fn < 4; fn++)
        acc[fm][fn] = __builtin_amdgcn_mfma_f32_16x16x32_bf16(afr[fm], bfr[fn], acc[fm][fn], 0, 0, 0);
    __builtin_amdgcn_s_setprio(0);
    block_barrier();

    // ---- phase 2: ks=0, mh=1 ----
#pragma unroll
    for (int fm = 0; fm < 4; fm++)
      afr[fm] = *(const bf16x8*)&As[buf][0][(wm * 128 + 64 + fm * 16 + lr) * 32 + kch];
    if (s1) {
      async16(Bg + kt1 + 32, &Bs[nbuf][1][l8]);
      async16(Bg + kt1 + 32 + rskip, &Bs[nbuf][1][l8 + 4096]);
    }
    block_barrier();
    __builtin_amdgcn_s_setprio(1);
#pragma unroll
    for (int fm = 0; fm < 4; fm++)
#pragma unroll
      for (int fn = 0; fn < 4; fn++)
        acc[4 + fm][fn] = __builtin_amdgcn_mfma_f32_16x16x32_bf16(afr[fm], bfr[fn], acc[4 + fm][fn], 0, 0, 0);
    __builtin_amdgcn_s_setprio(0);
    block_barrier();

    // ---- phase 3: ks=1, mh=0 ----
#pragma unroll
    for (int fm = 0; fm < 4; fm++)
      afr[fm] = *(const bf16x8*)&As[buf][1][(wm * 128 + fm * 16 + lr) * 32 + kch];
#pragma unroll
    for (int fn = 0; fn < 4; fn++)
      bfr[fn] = *(const bf16x8*)&Bs[buf][1][(wn * 64 + fn * 16 + lr) * 32 + kch];
    if (s2) {
      async16(Ag + kt2, &As[buf][0][l8]);
      async16(Ag + kt2 + rskip, &As[buf][0][l8 + 4096]);
    }
    block_barrier();
    __builtin_amdgcn_s_setprio(1);
#pragma unroll
    for (int fm = 0; fm < 4; fm++)
#pragma unroll
      for (int fn = 0; fn < 4; fn++)
        acc[fm][fn] = __builtin_amdgcn_mfma_f32_16x16x32_bf16(afr[fm], bfr[fn], acc[fm][fn], 0, 0, 0);
    __builtin_amdgcn_s_setprio(0);
    block_barrier();

    // ---- phase 4: ks=1, mh=1 ----
#pragma unroll
    for (int fm = 0; fm < 4; fm++)
      afr[fm] = *(const bf16x8*)&As[buf][1][(wm * 128 + 64 + fm * 16 + lr) * 32 + kch];
    if (s2) {
      async16(Bg + kt2, &Bs[buf][0][l8]);
      async16(Bg + kt2 + rskip, &Bs[buf][0][l8 + 4096]);
    }
    block_barrier();
    __builtin_amdgcn_s_setprio(1);
#pragma unroll
    for (int fm = 0; fm < 4; fm++)
#pragma unroll
      for (int fn = 0; fn < 4; fn++)
        acc[4 + fm][fn] = __builtin_amdgcn_mfma_f32_16x16x32_bf16(afr[fm], bfr[fn], acc[4 + fm][fn], 0, 0, 0);
    __builtin_amdgcn_s_setprio(0);
    if (s2) asm volatile("s_waitcnt vmcnt(4)" ::: "memory");
    else    asm volatile("s_waitcnt vmcnt(0)" ::: "memory");
    block_barrier();
  }

  // ---- coalesced epilogue: acc -> LDS (bf16, XOR-swizzled) -> wide stores.
  // Per-wave private 8 KB region of As (dead after the final barrier).
  // Write:  lds[row][ (fn ^ lg)*16 + lr ], row = fm*16+lg*4+r  (2 lanes/bank)
  // Read:   16B/lane, 8 lanes = 128B contiguous per row -> coalesced stores.
  unsigned short* wlds = &As[0][0][0] + wave * 4096;
  const bool vpath = (EPI == 4) && (n0 >= 2048);

#pragma unroll
  for (int mh = 0; mh < 2; ++mh) {
#pragma unroll
    for (int fn = 0; fn < 4; fn++) {
      const int col = n0 + wn * 64 + fn * 16 + lr;
      float bv = 0.0f;
      if (EPI == 2) bv = bias[col];
      const bool qscale = (EPI == 4) && (col < 1024);
#pragma unroll
      for (int fm = 0; fm < 4; fm++) {
#pragma unroll
        for (int r = 0; r < 4; r++) {
          float v = acc[mh * 4 + fm][fn][r];
          if (EPI == 2) v = fmaxf(v + bv, 0.0f);
          if (qscale) v *= 0.18033688011112042f;  // 0.125 * log2(e)
          wlds[(fm * 16 + lg * 4 + r) * 64 + (((fn ^ lg) << 4) | lr)] = f2bf(v);
        }
      }
    }
    asm volatile("s_waitcnt lgkmcnt(0)" ::: "memory");
    __builtin_amdgcn_sched_barrier(0);

    if (vpath) {
      // transposed V store: lane owns one col, 16B (8 rows) per pass
      const int colw = lane;
      const int fnr = colw >> 4, cin = colw & 15;
      unsigned short* dst = (unsigned short*)Cout2 +
          (size_t)(n0 - 2048 + wn * 64 + colw) * 4096 +
          (m0 + wm * 128 + mh * 64);
#pragma unroll
      for (int p = 0; p < 8; ++p) {
        unsigned short tmp[8];
#pragma unroll
        for (int j = 0; j < 8; ++j) {
          const int lrow = p * 8 + j;
          tmp[j] = wlds[lrow * 64 + (((fnr ^ ((lrow >> 2) & 3)) << 4) | cin)];
        }
        *(ushort4*)(dst + p * 8)     = *(ushort4*)&tmp[0];
        *(ushort4*)(dst + p * 8 + 4) = *(ushort4*)&tmp[4];
      }
    } else {
      const int fnr = (lane & 7) >> 1;
      const int coff = (lane & 1) << 3;
      const int gcol = n0 + wn * 64 + (lane & 7) * 8;
      const int Nst = (EPI == 4) ? 2048 : N;
      unsigned short* base;
      if (EPI == 5)
        base = (unsigned short*)(ks < 2 ? Cout : Cout2) + (size_t)(ks & 1) * M * N;
      else
        base = (unsigned short*)Cout;
#pragma unroll
      for (int p = 0; p < 8; ++p) {
        const int lrow = p * 8 + (lane >> 3);
        const bf16x8 v = *(const bf16x8*)
            &wlds[lrow * 64 + (((fnr ^ ((lrow >> 2) & 3)) << 4) | coff)];
        const size_t grow = (size_t)(m0 + wm * 128 + mh * 64 + lrow);
        *(bf16x8*)(base + grow * Nst + gcol) = v;
      }
    }
    asm volatile("s_waitcnt lgkmcnt(0)" ::: "memory");
    __builtin_amdgcn_sched_barrier(0);
  }
}

// ---------------------------------------------------------------------------
// Flash attention (causal), swapped-operand, LDS-staged K/V, double-buffered,
// exp2-domain softmax. 1024 blocks, XCD-grouped + LPT, 3 blocks/CU.
// ---------------------------------------------------------------------------
__global__ __launch_bounds__(256, 3) void attn_kernel(
    const unsigned short* __restrict__ qk, const unsigned short* __restrict__ vT,
    unsigned short* __restrict__ o) {
  const int T = 2048, C = 1024, QKS = 2048;
  const int tid = threadIdx.x;
  const int wave = tid >> 6, lane = tid & 63;
  const int lr = lane & 15, lg = lane >> 4;

  // decode XCD-grouped LPT mapping
  const int id = (int)blockIdx.x;
  const int rest = id >> 3;           // [0,128)
  const int bhHi = rest & 3;
  const int qt = 31 - (rest >> 2);    // longest first
  const int bh = (bhHi << 3) | (id & 7);
  const int b = bh >> 4, hh = bh & 15;

  const size_t rowb = (size_t)b * T * QKS;
  const int qcol = hh * 64;
  const int kcol = 1024 + hh * 64;
  const int vrow0 = hh * 64;
  const size_t bT = (size_t)b * T;
  const int swe = (lr & 7) << 3;

  __shared__ __align__(16) unsigned short Ks[2][64 * 64];
  __shared__ __align__(16) unsigned short Vs[2][64 * 64];
  __shared__ __align__(16) unsigned short Ps[4][16][72];

  const int rw = tid >> 3;
  const int c8 = ((tid & 7) ^ (rw & 7)) << 3;

  const int qbase = qt * 64 + wave * 16;
  const int trow = qbase + lr;

  U8 qf[2];
#pragma unroll
  for (int j = 0; j < 2; j++)
    qf[j].v = *(const bf16x8*)(qk + rowb + (size_t)trow * QKS + qcol + j * 32 + lg * 8);
  asm volatile("s_waitcnt vmcnt(0)" ::: "memory");

  async16(qk + rowb + (size_t)rw * QKS + kcol + c8, Ks[0] + tid * 8);
  async16(qk + rowb + (size_t)(32 + rw) * QKS + kcol + c8, Ks[0] + 2048 + tid * 8);
  async16(vT + (size_t)(vrow0 + rw) * 4096 + bT + c8, Vs[0] + tid * 8);
  async16(vT + (size_t)(vrow0 + 32 + rw) * 4096 + bT + c8, Vs[0] + 2048 + tid * 8);

  f32x4 oa[4] = {};
  float mrun = -1e30f, lsum = 0.0f;
  int cur = 0;

  for (int sb = 0; sb <= qt; ++sb) {
    if (sb < qt) {
      const int s1 = (sb + 1) * 64;
      const int nb = cur ^ 1;
      async16(qk + rowb + (size_t)(s1 + rw) * QKS + kcol + c8, Ks[nb] + tid * 8);
      async16(qk + rowb + (size_t)(s1 + 32 + rw) * QKS + kcol + c8, Ks[nb] + 2048 + tid * 8);
      async16(vT + (size_t)(vrow0 + rw) * 4096 + bT + s1 + c8, Vs[nb] + tid * 8);
      async16(vT + (size_t)(vrow0 + 32 + rw) * 4096 + bT + s1 + c8, Vs[nb] + 2048 + tid * 8);
      asm volatile("s_waitcnt vmcnt(4)" ::: "memory");
    } else {
      asm volatile("s_waitcnt vmcnt(0)" ::: "memory");
    }
    block_barrier();

    const unsigned short* Kc = Ks[cur];
    const unsigned short* Vc = Vs[cur];
    const int s0 = sb * 64;

    f32x4 sa[4] = {};
    __builtin_amdgcn_s_setprio(1);
#pragma unroll
    for (int j = 0; j < 2; j++) {
#pragma unroll
      for (int mf = 0; mf < 4; mf++) {
        U8 kf;
        kf.v = *(const bf16x8*)(Kc + (mf * 16 + lr) * 64 + ((j * 32 + lg * 8) ^ swe));
        sa[mf] = __builtin_amdgcn_mfma_f32_16x16x32_bf16(kf.v, qf[j].v, sa[mf], 0, 0, 0);
      }
    }
    __builtin_amdgcn_s_setprio(0);
    float sv[16];
#pragma unroll
    for (int mf = 0; mf < 4; mf++)
#pragma unroll
      for (int r = 0; r < 4; r++) sv[mf * 4 + r] = sa[mf][r];  // log2-scaled

    if (sb == qt) {
#pragma unroll
      for (int mf = 0; mf < 4; mf++)
#pragma unroll
        for (int r = 0; r < 4; r++)
          if (s0 + mf * 16 + lg * 4 + r > trow) sv[mf * 4 + r] = -1e30f;
    }

    float t8[8];
#pragma unroll
    for (int i = 0; i < 8; i++) t8[i] = fmaxf(sv[i], sv[i + 8]);
#pragma unroll
    for (int i = 0; i < 4; i++) t8[i] = fmaxf(t8[i], t8[i + 4]);
    float tm = fmaxf(fmaxf(t8[0], t8[1]), fmaxf(t8[2], t8[3]));
    tm = fmaxf(tm, __shfl_xor(tm, 16));
    tm = fmaxf(tm, __shfl_xor(tm, 32));

    if (!__all(tm <= mrun + 8.0f)) {  // defer-max (log2 units)
      const float mn = fmaxf(mrun, tm);
      const float corr = __builtin_amdgcn_exp2f(mrun - mn);
      lsum *= corr;
#pragma unroll
      for (int c = 0; c < 4; c++)
#pragma unroll
        for (int r = 0; r < 4; r++) oa[c][r] *= corr;
      mrun = mn;
    }

#pragma unroll
    for (int i = 0; i < 16; i++)
      sv[i] = __builtin_amdgcn_exp2f(sv[i] - mrun);
    float s8[8];
#pragma unroll
    for (int i = 0; i < 8; i++) s8[i] = sv[i] + sv[i + 8];
#pragma unroll
    for (int i = 0; i < 4; i++) s8[i] = s8[i] + s8[i + 4];
    float rs = (s8[0] + s8[1]) + (s8[2] + s8[3]);
    rs += __shfl_xor(rs, 16);
    rs += __shfl_xor(rs, 32);
    lsum += rs;

#pragma unroll
    for (int mf = 0; mf < 4; mf++) {
      ushort4 w;
      w.x = f2bf(sv[mf * 4 + 0]);
      w.y = f2bf(sv[mf * 4 + 1]);
      w.z = f2bf(sv[mf * 4 + 2]);
      w.w = f2bf(sv[mf * 4 + 3]);
      *(ushort4*)&Ps[wave][lr][mf * 16 + lg * 4] = w;
    }
    asm volatile("" ::: "memory");
    U8 pb[2];
    pb[0].v = *(const bf16x8*)&Ps[wave][lr][lg * 8];
    pb[1].v = *(const bf16x8*)&Ps[wave][lr][32 + lg * 8];
    asm volatile("" ::: "memory");

    __builtin_amdgcn_s_setprio(1);
#pragma unroll
    for (int c = 0; c < 4; c++) {
#pragma unroll
      for (int ks = 0; ks < 2; ks++) {
        U8 vf;
        vf.v = *(const bf16x8*)(Vc + (c * 16 + lr) * 64 + ((ks * 32 + lg * 8) ^ swe));
        oa[c] = __builtin_amdgcn_mfma_f32_16x16x32_bf16(vf.v, pb[ks].v, oa[c], 0, 0, 0);
      }
    }
    __builtin_amdgcn_s_setprio(0);

    block_barrier();
    cur ^= 1;
  }

  const float inv = 1.0f / lsum;
#pragma unroll
  for (int c = 0; c < 4; c++) {
    ushort4 ov;
    ov.x = f2bf(oa[c][0] * inv);
    ov.y = f2bf(oa[c][1] * inv);
    ov.z = f2bf(oa[c][2] * inv);
    ov.w = f2bf(oa[c][3] * inv);
    *(ushort4*)(o + (size_t)(bT + trow) * C + hh * 64 + c * 16 + lg * 4) = ov;
  }
}

// ---------------------------------------------------------------------------
// Orchestration.  Workspace lifetimes (80 MB):
//   0-6 WqkvT (dead after QKV) | 6-8 WpT (dead after proj) | 8-16 W1T (dead
//   after FFN1) | 16-24 W2T (thru FFN2) | 24-32 h (dead after QKV) |
//   32-48 qkb, 48-56 vTb (dead after attn) | 56-64 att -> h2 |
//   24-56 ff1 after FFN1 | x1 = d_out | FFN2 bf16 partials: 0-16 & 64-80.
// ---------------------------------------------------------------------------
extern "C" void kernel_launch(void* const* d_in, const int* in_sizes, int n_in,
                              void* d_out, int out_size, void* d_ws, size_t ws_size,
                              hipStream_t stream) {
  (void)in_sizes; (void)n_in; (void)out_size; (void)ws_size;
  const int T = 2048, C = 1024, M = 2 * T, C4 = 4 * C;

  const float* x     = (const float*)d_in[0];
  const float* Wq    = (const float*)d_in[1];
  const float* Wk    = (const float*)d_in[2];
  const float* Wv    = (const float*)d_in[3];
  const float* Wproj = (const float*)d_in[4];
  const float* bproj = (const float*)d_in[5];
  const float* W1    = (const float*)d_in[6];
  const float* b1    = (const float*)d_in[7];
  const float* W2    = (const float*)d_in[8];
  const float* b2    = (const float*)d_in[9];
  const float* ln1g  = (const float*)d_in[10];
  const float* ln1b  = (const float*)d_in[11];
  const float* ln2g  = (const float*)d_in[12];
  const float* ln2b  = (const float*)d_in[13];
  float* out = (float*)d_out;

  char* ws = (char*)d_ws;
  const size_t MBy = (size_t)1 << 20;
  unsigned short* WqkvT = (unsigned short*)(ws + 0 * MBy);
  unsigned short* WpT = (unsigned short*)(ws + 6 * MBy);
  unsigned short* W1T = (unsigned short*)(ws + 8 * MBy);
  unsigned short* W2T = (unsigned short*)(ws + 16 * MBy);
  unsigned short* h   = (unsigned short*)(ws + 24 * MBy);
  unsigned short* qkb = (unsigned short*)(ws + 32 * MBy);
  unsigned short* vTb = (unsigned short*)(ws + 48 * MBy);
  unsigned short* att = (unsigned short*)(ws + 56 * MBy);
  float* x1 = out;                                    // x1 lives in d_out
  unsigned short* h2  = att;
  unsigned short* ff1 = h;
  unsigned short* ffP01 = (unsigned short*)(ws + 0 * MBy);   // planes 0,1
  unsigned short* ffP23 = (unsigned short*)(ws + 64 * MBy);  // planes 2,3

  const dim3 tb(32, 8);
  transpose_qkv<<<dim3(2, 32, 48), tb, 0, stream>>>(Wq, Wk, Wv, WqkvT);
  transpose_w<<<dim3(32, 32, 1), tb, 0, stream>>>(Wproj, WpT, 1024, 1024);
  transpose_w<<<dim3(128, 32, 1), tb, 0, stream>>>(W1, W1T, 1024, 4096);
  transpose_w<<<dim3(32, 128, 1), tb, 0, stream>>>(W2, W2T, 4096, 1024);

  ln_kernel<<<M, 256, 0, stream>>>(x, ln1g, ln1b, h);

  // Fused QKV (8-phase 256^2): Q cols pre-scaled by 0.125*log2e
  gemm8p<4, 1><<<192, 512, 0, stream>>>(h, WqkvT, qkb, vTb, nullptr, M, 3072, C);

  // attn: 1024 blocks, XCD-grouped + LPT, 3 blocks/CU
  attn_kernel<<<1024, 256, 0, stream>>>(qkb, vTb, att);

  // proj (+bproj +x) -> x1 (d_out)
  gemm_lat2<<<512, 256, 0, stream>>>(att, WpT, x1, bproj, x, M, C, C);

  ln_kernel<<<M, 256, 0, stream>>>(x1, ln2g, ln2b, h2);

  // FFN1 (8-phase 256^2): relu(h2 @ W1 + b1) -> bf16
  gemm8p<2, 1><<<256, 512, 0, stream>>>(h2, W1T, ff1, nullptr, b1, M, C4, C);

  // FFN2: split-K=4 8-phase partials (bf16) + fused reduce (+b2 +x1 in-place)
  gemm8p<5, 4><<<256, 512, 0, stream>>>(ff1, W2T, ffP01, ffP23, nullptr, M, C, C4);
  reduce_add4<<<2048, 256, 0, stream>>>(ffP01, ffP23, b2, out, M * C / 4);
}